// Round 3
// baseline (300.302 us; speedup 1.0000x reference)
//
#include <hip/hip_runtime.h>
#include <stdint.h>

// ---------- types ----------
typedef __attribute__((ext_vector_type(8))) short short8;   // 8 x bf16 (raw)
typedef __attribute__((ext_vector_type(4))) float f32x4;

typedef const __attribute__((address_space(1))) void gv_t;
typedef __attribute__((address_space(3))) void lv_t;

__device__ __forceinline__ void gl_lds16(const void* g, void* l) {
    // async global->LDS, 16B per lane; LDS dest must be waveBase + lane*16
    __builtin_amdgcn_global_load_lds((gv_t*)g, (lv_t*)l, 16, 0, 0);
}

__device__ __forceinline__ unsigned short f2bf(float f) {
    union { float f; unsigned int u; } v; v.f = f;
    unsigned int r = v.u + 0x7fffu + ((v.u >> 16) & 1u);   // RNE
    return (unsigned short)(r >> 16);
}

__device__ __forceinline__ f32x4 zero4() { f32x4 z = {0.f, 0.f, 0.f, 0.f}; return z; }

// ---------- prep kernels (fp32 inputs -> bf16 working set) ----------
__global__ void k_cvt(const float* __restrict__ y, unsigned short* __restrict__ yb) {
    int i = (blockIdx.x * 256 + threadIdx.x) * 4;
    float4 v = *(const float4*)(y + i);
    union { unsigned short u[4]; uint2 w; } o;
    o.u[0] = f2bf(v.x); o.u[1] = f2bf(v.y); o.u[2] = f2bf(v.z); o.u[3] = f2bf(v.w);
    *(uint2*)(yb + i) = o.w;
}

__global__ void k_wqkv(const float* __restrict__ W,
                       const float* __restrict__ Bq, const float* __restrict__ Aq,
                       const float* __restrict__ Bk, const float* __restrict__ Ak,
                       const float* __restrict__ Bv, const float* __restrict__ Av,
                       unsigned short* __restrict__ out) {
    int idx = blockIdx.x * 256 + threadIdx.x;     // n*1024 + k
    int n = idx >> 10, k = idx & 1023;
    int sel = n >> 10, n0 = n & 1023;
    const float* Bp = (sel == 0) ? Bq : (sel == 1) ? Bk : Bv;
    const float* Ap = (sel == 0) ? Aq : (sel == 1) ? Ak : Av;
    float acc = W[idx];
    #pragma unroll
    for (int r = 0; r < 8; ++r) acc += Bp[k * 8 + r] * Ap[r * 1024 + n0];
    out[idx] = f2bf(acc);
}

__global__ void k_wmsa(const float* __restrict__ W,
                       const float* __restrict__ Bo, const float* __restrict__ Ao,
                       unsigned short* __restrict__ out) {
    int idx = blockIdx.x * 256 + threadIdx.x;     // n*1024 + k
    int n = idx >> 10, k = idx & 1023;
    float acc = W[idx];
    #pragma unroll
    for (int r = 0; r < 8; ++r) acc += Bo[k * 8 + r] * Ao[r * 1024 + n];
    out[idx] = f2bf(acc);
}

// ---------- GEMM: C[M,N] = A[M,K](bf16) @ B[N,K]^T(bf16)  (m97 structure) ----------
// EPI=0: C = bf16(acc + bias[col])   EPI=1: C = fp32(acc + yres[row,col]) (bias/yres fp32)
template <int EPI>
__global__ __launch_bounds__(256, 2) void k_gemm(const unsigned short* __restrict__ Ag,
                                                 const unsigned short* __restrict__ Bg,
                                                 const float* __restrict__ bias,
                                                 const float* __restrict__ yres,
                                                 void* __restrict__ Cout,
                                                 int M, int N, int K) {
    __shared__ unsigned short As[128 * 32];
    __shared__ unsigned short Bs[128 * 32];
    const int flat = threadIdx.x;
    const int m0 = blockIdx.y * 128, n0 = blockIdx.x * 128;
    const int lane = flat & 63, wave = flat >> 6;
    const int l16 = lane & 15, quad = lane >> 4;
    const int wm = (wave >> 1) * 64, wn = (wave & 1) * 64;

    f32x4 acc[4][4];
    #pragma unroll
    for (int mi = 0; mi < 4; ++mi)
        #pragma unroll
        for (int ni = 0; ni < 4; ++ni) acc[mi][ni] = zero4();

    const unsigned short* ap = Ag + (size_t)(m0 + (flat >> 2)) * K + (flat & 3) * 8;
    const unsigned short* bp = Bg + (size_t)(n0 + (flat >> 2)) * K + (flat & 3) * 8;
    const size_t rstep = (size_t)64 * K;

    for (int k0 = 0; k0 < K; k0 += 32) {
        __syncthreads();
        gl_lds16(ap,         &As[flat * 8]);
        gl_lds16(ap + rstep, &As[2048 + flat * 8]);
        gl_lds16(bp,         &Bs[flat * 8]);
        gl_lds16(bp + rstep, &Bs[2048 + flat * 8]);
        ap += 32; bp += 32;
        __syncthreads();

        short8 af[4], bfr[4];
        #pragma unroll
        for (int i = 0; i < 4; ++i) af[i] = *(const short8*)&As[(wm + i * 16 + l16) * 32 + quad * 8];
        #pragma unroll
        for (int i = 0; i < 4; ++i) bfr[i] = *(const short8*)&Bs[(wn + i * 16 + l16) * 32 + quad * 8];
        #pragma unroll
        for (int mi = 0; mi < 4; ++mi)
            #pragma unroll
            for (int ni = 0; ni < 4; ++ni)
                acc[mi][ni] = __builtin_amdgcn_mfma_f32_16x16x32_bf16(af[mi], bfr[ni], acc[mi][ni], 0, 0, 0);
    }

    // epilogue: C/D layout col=lane&15, row=quad*4+reg
    if (EPI == 0) {
        unsigned short* C = (unsigned short*)Cout;
        #pragma unroll
        for (int ni = 0; ni < 4; ++ni) {
            int col = n0 + wn + ni * 16 + l16;
            float bv = bias[col];
            #pragma unroll
            for (int mi = 0; mi < 4; ++mi) {
                int row = m0 + wm + mi * 16 + quad * 4;
                #pragma unroll
                for (int r = 0; r < 4; ++r)
                    C[(size_t)(row + r) * N + col] = f2bf(acc[mi][ni][r] + bv);
            }
        }
    } else {
        float* C = (float*)Cout;
        #pragma unroll
        for (int ni = 0; ni < 4; ++ni) {
            int col = n0 + wn + ni * 16 + l16;
            #pragma unroll
            for (int mi = 0; mi < 4; ++mi) {
                int row = m0 + wm + mi * 16 + quad * 4;
                #pragma unroll
                for (int r = 0; r < 4; ++r)
                    C[(size_t)(row + r) * N + col] = acc[mi][ni][r] + yres[(size_t)(row + r) * N + col];
            }
        }
    }
}

// ---------- fused flash attention ----------
// qkv: [4096 tok][3072] bf16 (Q | K | V per head h at cols h*64).
// One block = (b, h, 128-row q-tile). Computes S^T = K @ Q^T so that P exits the
// MFMA with 4 consecutive k per reg group (packed 8B LDS writes) and PV A-operand
// reads are contiguous b128. Strides padded to 72 (144B) to avoid bank conflicts.
__global__ __launch_bounds__(256, 2) void k_attn(const unsigned short* __restrict__ qkv,
                                                 unsigned short* __restrict__ o) {
    __shared__ unsigned short LDS[27648];          // 54 KB
    unsigned short* Qs = LDS;                      // [128][72]
    unsigned short* Ks = LDS + 128 * 72;           // [64][72]
    unsigned short* Vt = LDS + 128 * 72 + 64 * 72; // [64][72]  (V^T: row d, col k)
    unsigned short* Ps = LDS + 128 * 72 + 2 * 64 * 72; // [128][72] (row q, col k)

    const int t = threadIdx.x;
    const int lane = t & 63, wave = t >> 6;
    const int l16 = lane & 15, quad = lane >> 4;
    const int q0 = blockIdx.x * 128;
    const int h = blockIdx.y, b = blockIdx.z;

    const unsigned short* qbase = qkv + (size_t)(b * 2048) * 3072 + h * 64;
    const unsigned short* kbase = qbase + 1024;
    const unsigned short* vbase = qbase + 2048;

    // stage Q tile [128][64] -> Qs (stride 72)
    #pragma unroll
    for (int i = 0; i < 4; ++i) {
        int cid = i * 256 + t;                    // 0..1023
        int qr = cid >> 3, c = cid & 7;
        short8 v = *(const short8*)(qbase + (size_t)(q0 + qr) * 3072 + c * 8);
        *(short8*)&Qs[qr * 72 + c * 8] = v;
    }
    __syncthreads();

    // preload Q B-fragments (invariant over k-loop): B[n=q][k=d]
    short8 qf[2][2];
    #pragma unroll
    for (int ni = 0; ni < 2; ++ni)
        #pragma unroll
        for (int kk = 0; kk < 2; ++kk)
            qf[ni][kk] = *(const short8*)&Qs[(wave * 32 + ni * 16 + l16) * 72 + kk * 32 + quad * 8];

    f32x4 acc_o[2][4];
    #pragma unroll
    for (int mo = 0; mo < 2; ++mo)
        #pragma unroll
        for (int nd = 0; nd < 4; ++nd) acc_o[mo][nd] = zero4();
    float m2[2] = {-3.0e38f, -3.0e38f};
    float lsum[2] = {0.f, 0.f};
    const float SC = 0.125f * 1.44269504088896340736f;   // 1/sqrt(64) * log2(e)

    for (int j = 0; j < 32; ++j) {
        __syncthreads();
        // stage K tile [64][64] -> Ks (stride 72)
        #pragma unroll
        for (int i = 0; i < 2; ++i) {
            int cid = i * 256 + t;                // 0..511
            int kr = cid >> 3, c = cid & 7;
            short8 v = *(const short8*)(kbase + (size_t)(j * 64 + kr) * 3072 + c * 8);
            *(short8*)&Ks[kr * 72 + c * 8] = v;
        }
        // stage V tile transposed -> Vt[d][k] (stride 72), lane-staggered to spread banks
        {
            int d0 = (t & 7) * 8, k2 = (t >> 3) * 2;
            short8 v0 = *(const short8*)(vbase + (size_t)(j * 64 + k2) * 3072 + d0);
            short8 v1 = *(const short8*)(vbase + (size_t)(j * 64 + k2 + 1) * 3072 + d0);
            #pragma unroll
            for (int jj = 0; jj < 8; ++jj) {
                int js = (jj + (t & 7)) & 7;
                unsigned int pk = (unsigned short)v0[js] | ((unsigned int)(unsigned short)v1[js] << 16);
                *(unsigned int*)&Vt[(d0 + js) * 72 + k2] = pk;
            }
        }
        __syncthreads();

        // S^T = K @ Q^T : per wave [64 k x 32 q]; A=K rows, B=Q^T
        f32x4 sacc[4][2];
        #pragma unroll
        for (int mi = 0; mi < 4; ++mi)
            #pragma unroll
            for (int ni = 0; ni < 2; ++ni) sacc[mi][ni] = zero4();
        #pragma unroll
        for (int kk = 0; kk < 2; ++kk)
            #pragma unroll
            for (int mi = 0; mi < 4; ++mi) {
                short8 kf = *(const short8*)&Ks[(mi * 16 + l16) * 72 + kk * 32 + quad * 8];
                #pragma unroll
                for (int ni = 0; ni < 2; ++ni)
                    sacc[mi][ni] = __builtin_amdgcn_mfma_f32_16x16x32_bf16(kf, qf[ni][kk], sacc[mi][ni], 0, 0, 0);
            }

        // online softmax over k (rows of S^T). lane owns cols q = wave*32 + ni*16 + l16
        float mnew[2], alpha[2];
        #pragma unroll
        for (int ni = 0; ni < 2; ++ni) {
            float mt = -3.0e38f;
            #pragma unroll
            for (int mi = 0; mi < 4; ++mi)
                #pragma unroll
                for (int rr = 0; rr < 4; ++rr) mt = fmaxf(mt, sacc[mi][ni][rr]);
            mt *= SC;
            mt = fmaxf(mt, __shfl_xor(mt, 16));
            mt = fmaxf(mt, __shfl_xor(mt, 32));
            mnew[ni] = fmaxf(m2[ni], mt);
            alpha[ni] = exp2f(m2[ni] - mnew[ni]);
            m2[ni] = mnew[ni];
        }

        // rescale O accumulator (rows need alpha of their q-row -> shfl within 16-group)
        #pragma unroll
        for (int mo = 0; mo < 2; ++mo)
            #pragma unroll
            for (int rr = 0; rr < 4; ++rr) {
                float ar = __shfl(alpha[mo], quad * 4 + rr, 16);
                #pragma unroll
                for (int nd = 0; nd < 4; ++nd) acc_o[mo][nd][rr] *= ar;
            }

        // P = exp2(s*SC - m), write bf16 to Ps[q][k] (4 consecutive k per 8B write)
        float rs[2] = {0.f, 0.f};
        #pragma unroll
        for (int ni = 0; ni < 2; ++ni)
            #pragma unroll
            for (int mi = 0; mi < 4; ++mi) {
                union { unsigned short u[4]; uint2 w; } pk;
                #pragma unroll
                for (int rr = 0; rr < 4; ++rr) {
                    float p = exp2f(sacc[mi][ni][rr] * SC - mnew[ni]);
                    rs[ni] += p;
                    pk.u[rr] = f2bf(p);
                }
                *(uint2*)&Ps[(wave * 32 + ni * 16 + l16) * 72 + mi * 16 + quad * 4] = pk.w;
            }
        #pragma unroll
        for (int ni = 0; ni < 2; ++ni) {
            float r = rs[ni];
            r += __shfl_xor(r, 16);
            r += __shfl_xor(r, 32);
            lsum[ni] = lsum[ni] * alpha[ni] + r;
        }

        // PV: O[q][d] += P @ V. Same-wave LDS RAW on Ps (DS pipe is in-order per wave).
        #pragma unroll
        for (int kk = 0; kk < 2; ++kk) {
            short8 pf[2];
            #pragma unroll
            for (int mo = 0; mo < 2; ++mo)
                pf[mo] = *(const short8*)&Ps[(wave * 32 + mo * 16 + l16) * 72 + kk * 32 + quad * 8];
            #pragma unroll
            for (int nd = 0; nd < 4; ++nd) {
                short8 vf = *(const short8*)&Vt[(nd * 16 + l16) * 72 + kk * 32 + quad * 8];
                #pragma unroll
                for (int mo = 0; mo < 2; ++mo)
                    acc_o[mo][nd] = __builtin_amdgcn_mfma_f32_16x16x32_bf16(pf[mo], vf, acc_o[mo][nd], 0, 0, 0);
            }
        }
    }

    // epilogue: normalize by l and store o[tok][h*64+d] bf16
    #pragma unroll
    for (int mo = 0; mo < 2; ++mo)
        #pragma unroll
        for (int rr = 0; rr < 4; ++rr) {
            float lr = __shfl(lsum[mo], quad * 4 + rr, 16);
            float inv = 1.f / lr;
            int qg = q0 + wave * 32 + mo * 16 + quad * 4 + rr;
            size_t base = ((size_t)(b * 2048 + qg)) * 1024 + h * 64;
            #pragma unroll
            for (int nd = 0; nd < 4; ++nd)
                o[base + nd * 16 + l16] = f2bf(acc_o[mo][nd][rr] * inv);
        }
}

// ---------- LayerNorm (row=token, 1024 cols), fp32 in/out ----------
__global__ __launch_bounds__(256) void k_ln(const float* __restrict__ res,
                                            const float* __restrict__ g,
                                            const float* __restrict__ be,
                                            float* __restrict__ out) {
    __shared__ float red[8];
    const int row = blockIdx.x, t = threadIdx.x;
    const float* x = res + (size_t)row * 1024;
    float4 v = *(const float4*)(x + t * 4);
    float s = v.x + v.y + v.z + v.w;
    float sq = v.x * v.x + v.y * v.y + v.z * v.z + v.w * v.w;
    #pragma unroll
    for (int off = 32; off; off >>= 1) { s += __shfl_down(s, off); sq += __shfl_down(sq, off); }
    if ((t & 63) == 0) { red[t >> 6] = s; red[4 + (t >> 6)] = sq; }
    __syncthreads();
    float ts = red[0] + red[1] + red[2] + red[3];
    float tq = red[4] + red[5] + red[6] + red[7];
    float mu = ts * (1.f / 1024.f);
    float var = tq * (1.f / 1024.f) - mu * mu;
    float rstd = rsqrtf(var + 1e-6f);
    float4 gg = *(const float4*)(g + t * 4);
    float4 bb = *(const float4*)(be + t * 4);
    float4 ov;
    ov.x = (v.x - mu) * rstd * gg.x + bb.x;
    ov.y = (v.y - mu) * rstd * gg.y + bb.y;
    ov.z = (v.z - mu) * rstd * gg.z + bb.z;
    ov.w = (v.w - mu) * rstd * gg.w + bb.w;
    *(float4*)(out + (size_t)row * 1024 + t * 4) = ov;
}

// ---------- launch ----------
extern "C" void kernel_launch(void* const* d_in, const int* in_sizes, int n_in,
                              void* d_out, int out_size, void* d_ws, size_t ws_size,
                              hipStream_t stream) {
    (void)in_sizes; (void)n_in; (void)out_size; (void)ws_size;
    const float* y    = (const float*)d_in[0];
    const float* Wqkv = (const float*)d_in[1];
    const float* bqkv = (const float*)d_in[2];
    const float* Wmsa = (const float*)d_in[3];
    const float* Bq = (const float*)d_in[4];
    const float* Aq = (const float*)d_in[5];
    const float* Bk = (const float*)d_in[6];
    const float* Ak = (const float*)d_in[7];
    const float* Bv = (const float*)d_in[8];
    const float* Av = (const float*)d_in[9];
    const float* Bo = (const float*)d_in[10];
    const float* Ao = (const float*)d_in[11];
    const float* gamma = (const float*)d_in[12];
    const float* beta  = (const float*)d_in[13];

    char* ws = (char*)d_ws;
    unsigned short* yb   = (unsigned short*)(ws);               // 8 MB [4096][1024] bf16(y); reused as obuf
    unsigned short* weq  = (unsigned short*)(ws + (8u  << 20)); // 6 MB [3072][1024]
    unsigned short* wem  = (unsigned short*)(ws + (14u << 20)); // 2 MB [1024][1024]
    unsigned short* qkv  = (unsigned short*)(ws + (16u << 20)); // 24 MB [4096][3072]; reused as res (fp32 16 MB)
    unsigned short* obuf = yb;
    float* res = (float*)qkv;

    k_cvt <<<4096, 256, 0, stream>>>(y, yb);
    k_wqkv<<<12288, 256, 0, stream>>>(Wqkv, Bq, Aq, Bk, Ak, Bv, Av, weq);
    k_wmsa<<<4096, 256, 0, stream>>>(Wmsa, Bo, Ao, wem);
    k_gemm<0><<<dim3(24, 32), 256, 0, stream>>>(yb, weq, bqkv, nullptr, (void*)qkv, 4096, 3072, 1024);
    k_attn<<<dim3(16, 16, 2), 256, 0, stream>>>(qkv, obuf);
    k_gemm<1><<<dim3(8, 32), 256, 0, stream>>>(obuf, wem, nullptr, y, (void*)res, 4096, 1024, 1024);
    k_ln  <<<4096, 256, 0, stream>>>(res, gamma, beta, (float*)d_out);
}

// Round 4
// 269.368 us; speedup vs baseline: 1.1148x; 1.1148x over previous
//
#include <hip/hip_runtime.h>
#include <hip/hip_bf16.h>
#include <stdint.h>

// ---------- types ----------
typedef __attribute__((ext_vector_type(8))) short short8;   // 8 x bf16 (raw)
typedef __attribute__((ext_vector_type(4))) float f32x4;

typedef const __attribute__((address_space(1))) void gv_t;
typedef __attribute__((address_space(3))) void lv_t;

__device__ __forceinline__ void gl_lds16(const void* g, void* l) {
    // async global->LDS, 16B per lane; LDS dest must be waveBase + lane*16
    __builtin_amdgcn_global_load_lds((gv_t*)g, (lv_t*)l, 16, 0, 0);
}

__device__ __forceinline__ unsigned short f2bf(float f) {
    union { float f; unsigned int u; } v; v.f = f;
    unsigned int r = v.u + 0x7fffu + ((v.u >> 16) & 1u);   // RNE
    return (unsigned short)(r >> 16);
}

__device__ __forceinline__ unsigned int pack2bf(float a, float b) {
    union { __hip_bfloat162 h2; unsigned int u; } cv;
    cv.h2 = __float22bfloat162_rn(make_float2(a, b));   // v_cvt_pk_bf16_f32 on gfx950
    return cv.u;                                        // low = a, high = b
}

__device__ __forceinline__ f32x4 zero4() { f32x4 z = {0.f, 0.f, 0.f, 0.f}; return z; }

// ---------- prep kernels (fp32 inputs -> bf16 working set) ----------
__global__ void k_cvt(const float* __restrict__ y, unsigned short* __restrict__ yb) {
    int i = (blockIdx.x * 256 + threadIdx.x) * 4;
    float4 v = *(const float4*)(y + i);
    union { unsigned short u[4]; uint2 w; } o;
    o.u[0] = f2bf(v.x); o.u[1] = f2bf(v.y); o.u[2] = f2bf(v.z); o.u[3] = f2bf(v.w);
    *(uint2*)(yb + i) = o.w;
}

__global__ void k_wqkv(const float* __restrict__ W,
                       const float* __restrict__ Bq, const float* __restrict__ Aq,
                       const float* __restrict__ Bk, const float* __restrict__ Ak,
                       const float* __restrict__ Bv, const float* __restrict__ Av,
                       unsigned short* __restrict__ out) {
    int idx = blockIdx.x * 256 + threadIdx.x;     // n*1024 + k
    int n = idx >> 10, k = idx & 1023;
    int sel = n >> 10, n0 = n & 1023;
    const float* Bp = (sel == 0) ? Bq : (sel == 1) ? Bk : Bv;
    const float* Ap = (sel == 0) ? Aq : (sel == 1) ? Ak : Av;
    float acc = W[idx];
    #pragma unroll
    for (int r = 0; r < 8; ++r) acc += Bp[k * 8 + r] * Ap[r * 1024 + n0];
    out[idx] = f2bf(acc);
}

__global__ void k_wmsa(const float* __restrict__ W,
                       const float* __restrict__ Bo, const float* __restrict__ Ao,
                       unsigned short* __restrict__ out) {
    int idx = blockIdx.x * 256 + threadIdx.x;     // n*1024 + k
    int n = idx >> 10, k = idx & 1023;
    float acc = W[idx];
    #pragma unroll
    for (int r = 0; r < 8; ++r) acc += Bo[k * 8 + r] * Ao[r * 1024 + n];
    out[idx] = f2bf(acc);
}

// ---------- GEMM: C[M,N] = A[M,K](bf16) @ B[N,K]^T(bf16)  (m97 structure) ----------
template <int EPI>
__global__ __launch_bounds__(256, 2) void k_gemm(const unsigned short* __restrict__ Ag,
                                                 const unsigned short* __restrict__ Bg,
                                                 const float* __restrict__ bias,
                                                 const float* __restrict__ yres,
                                                 void* __restrict__ Cout,
                                                 int M, int N, int K) {
    __shared__ unsigned short As[128 * 32];
    __shared__ unsigned short Bs[128 * 32];
    const int flat = threadIdx.x;
    const int m0 = blockIdx.y * 128, n0 = blockIdx.x * 128;
    const int lane = flat & 63, wave = flat >> 6;
    const int l16 = lane & 15, quad = lane >> 4;
    const int wm = (wave >> 1) * 64, wn = (wave & 1) * 64;

    f32x4 acc[4][4];
    #pragma unroll
    for (int mi = 0; mi < 4; ++mi)
        #pragma unroll
        for (int ni = 0; ni < 4; ++ni) acc[mi][ni] = zero4();

    const unsigned short* ap = Ag + (size_t)(m0 + (flat >> 2)) * K + (flat & 3) * 8;
    const unsigned short* bp = Bg + (size_t)(n0 + (flat >> 2)) * K + (flat & 3) * 8;
    const size_t rstep = (size_t)64 * K;

    for (int k0 = 0; k0 < K; k0 += 32) {
        __syncthreads();
        gl_lds16(ap,         &As[flat * 8]);
        gl_lds16(ap + rstep, &As[2048 + flat * 8]);
        gl_lds16(bp,         &Bs[flat * 8]);
        gl_lds16(bp + rstep, &Bs[2048 + flat * 8]);
        ap += 32; bp += 32;
        __syncthreads();

        short8 af[4], bfr[4];
        #pragma unroll
        for (int i = 0; i < 4; ++i) af[i] = *(const short8*)&As[(wm + i * 16 + l16) * 32 + quad * 8];
        #pragma unroll
        for (int i = 0; i < 4; ++i) bfr[i] = *(const short8*)&Bs[(wn + i * 16 + l16) * 32 + quad * 8];
        #pragma unroll
        for (int mi = 0; mi < 4; ++mi)
            #pragma unroll
            for (int ni = 0; ni < 4; ++ni)
                acc[mi][ni] = __builtin_amdgcn_mfma_f32_16x16x32_bf16(af[mi], bfr[ni], acc[mi][ni], 0, 0, 0);
    }

    // epilogue: C/D layout col=lane&15, row=quad*4+reg
    if (EPI == 0) {
        unsigned short* C = (unsigned short*)Cout;
        #pragma unroll
        for (int ni = 0; ni < 4; ++ni) {
            int col = n0 + wn + ni * 16 + l16;
            float bv = bias[col];
            #pragma unroll
            for (int mi = 0; mi < 4; ++mi) {
                int row = m0 + wm + mi * 16 + quad * 4;
                #pragma unroll
                for (int r = 0; r < 4; ++r)
                    C[(size_t)(row + r) * N + col] = f2bf(acc[mi][ni][r] + bv);
            }
        }
    } else {
        float* C = (float*)Cout;
        #pragma unroll
        for (int ni = 0; ni < 4; ++ni) {
            int col = n0 + wn + ni * 16 + l16;
            #pragma unroll
            for (int mi = 0; mi < 4; ++mi) {
                int row = m0 + wm + mi * 16 + quad * 4;
                #pragma unroll
                for (int r = 0; r < 4; ++r)
                    C[(size_t)(row + r) * N + col] = acc[mi][ni][r] + yres[(size_t)(row + r) * N + col];
            }
        }
    }
}

// ---------- V transpose: qkv V-part -> vtg[b,h][d][k] (k contiguous) ----------
__global__ __launch_bounds__(256) void k_vt(const unsigned short* __restrict__ qkv,
                                            unsigned short* __restrict__ vtg) {
    __shared__ unsigned short T[64 * 72];
    const int t = threadIdx.x;
    const int k0 = blockIdx.x * 64, h = blockIdx.y, b = blockIdx.z;
    const unsigned short* vbase = qkv + (size_t)(b * 2048) * 3072 + 2048 + h * 64;
    #pragma unroll
    for (int i = 0; i < 2; ++i) {
        int B = i * 256 + t;                       // 0..511
        int row = B >> 3, c = B & 7;
        short8 v = *(const short8*)(vbase + (size_t)(k0 + row) * 3072 + c * 8);
        *(short8*)&T[row * 72 + c * 8] = v;
    }
    __syncthreads();
    unsigned short* obase = vtg + ((size_t)((b * 16 + h) * 64)) * 2048 + k0;
    #pragma unroll
    for (int i = 0; i < 2; ++i) {
        int B = i * 256 + t;
        int d = B >> 3, kc = B & 7;
        union { unsigned short u[8]; short8 v; } pk;
        #pragma unroll
        for (int jj = 0; jj < 8; ++jj) pk.u[jj] = T[(kc * 8 + jj) * 72 + d];
        *(short8*)(obase + (size_t)d * 2048 + kc * 8) = pk.v;
    }
}

// ---------- fused flash attention (static-max softmax, swizzled LDS, async staging) ----------
// Tiles stored as 64-short rows; 16B chunk c of row r lives at chunk slot c^(r&7).
__global__ __launch_bounds__(256, 2) void k_attn(const unsigned short* __restrict__ qkv,
                                                 const unsigned short* __restrict__ vtg,
                                                 unsigned short* __restrict__ o) {
    __shared__ unsigned short LDS[16384];          // 32 KB
    unsigned short* Qs = LDS;                      // [128][64] swizzled (aliased by Ps after preload)
    unsigned short* Ks = LDS + 8192;               // [64][64]
    unsigned short* Vt = LDS + 12288;              // [64][64]  (rows=d, cols=k)
    unsigned short* Ps = LDS;                      // [128][64] (rows=q, cols=k) — aliases Qs

    const int t = threadIdx.x;
    const int lane = t & 63, wave = t >> 6;
    const int l16 = lane & 15, quad = lane >> 4;
    const int l8 = l16 & 7;
    const int q0 = blockIdx.x * 128;
    const int h = blockIdx.y, b = blockIdx.z;

    const unsigned short* qbase = qkv + (size_t)(b * 2048) * 3072 + h * 64;
    const unsigned short* kbase = qbase + 1024;
    const unsigned short* vtbase = vtg + (size_t)((b * 16 + h) * 64) * 2048;

    // stage Q tile [128][64] swizzled, via global_load_lds
    #pragma unroll
    for (int i = 0; i < 4; ++i) {
        int B = i * 256 + t;                       // 16B-block index 0..1023
        int row = B >> 3, c = (B & 7) ^ (row & 7);
        gl_lds16(qbase + (size_t)(q0 + row) * 3072 + c * 8, &Qs[B * 8]);
    }

    // per-lane staging constants for K / Vt tiles (512 blocks each, 2 calls)
    const int B0 = t, B1 = t + 256;
    const int r0 = B0 >> 3, c0 = (B0 & 7) ^ (r0 & 7);
    const int r1 = B1 >> 3, c1 = (B1 & 7) ^ (r1 & 7);
    const unsigned short* kp0 = kbase + (size_t)r0 * 3072 + c0 * 8;
    const unsigned short* kp1 = kbase + (size_t)r1 * 3072 + c1 * 8;
    const unsigned short* vp0 = vtbase + (size_t)r0 * 2048 + c0 * 8;
    const unsigned short* vp1 = vtbase + (size_t)r1 * 2048 + c1 * 8;

    __syncthreads();                               // Q staged & visible

    // preload Q B-fragments (loop-invariant): B[n=q][k=d]
    short8 qf[2][2];
    #pragma unroll
    for (int ni = 0; ni < 2; ++ni)
        #pragma unroll
        for (int kk = 0; kk < 2; ++kk)
            qf[ni][kk] = *(const short8*)&Qs[(wave * 32 + ni * 16 + l16) * 64 + ((kk * 4 + quad) ^ l8) * 8];

    f32x4 acc_o[2][4];
    #pragma unroll
    for (int mo = 0; mo < 2; ++mo)
        #pragma unroll
        for (int nd = 0; nd < 4; ++nd) acc_o[mo][nd] = zero4();
    float lsum[2] = {0.f, 0.f};
    const float SC  = 0.18033688011112042f;        // log2(e)/sqrt(64)
    const float MST = 8.0f;                        // static max (cancels exactly; fp32 range safe)

    for (int j = 0; j < 32; ++j) {
        __syncthreads();                           // all waves done with previous K/Vt (and Ps/Qs reads)
        gl_lds16(kp0, &Ks[B0 * 8]);
        gl_lds16(kp1, &Ks[B1 * 8]);
        gl_lds16(vp0, &Vt[B0 * 8]);
        gl_lds16(vp1, &Vt[B1 * 8]);
        kp0 += 64 * 3072; kp1 += 64 * 3072; vp0 += 64; vp1 += 64;
        __syncthreads();                           // vmcnt drained, tiles visible

        // S^T = K @ Q^T : per wave [64 k x 32 q]
        f32x4 sacc[4][2];
        #pragma unroll
        for (int mi = 0; mi < 4; ++mi)
            #pragma unroll
            for (int ni = 0; ni < 2; ++ni) sacc[mi][ni] = zero4();
        #pragma unroll
        for (int kk = 0; kk < 2; ++kk)
            #pragma unroll
            for (int mi = 0; mi < 4; ++mi) {
                short8 kf = *(const short8*)&Ks[(mi * 16 + l16) * 64 + ((kk * 4 + quad) ^ l8) * 8];
                #pragma unroll
                for (int ni = 0; ni < 2; ++ni)
                    sacc[mi][ni] = __builtin_amdgcn_mfma_f32_16x16x32_bf16(kf, qf[ni][kk], sacc[mi][ni], 0, 0, 0);
            }

        // static-max softmax: p = exp2(s*SC - MST); accumulate per-lane partial l
        #pragma unroll
        for (int ni = 0; ni < 2; ++ni) {
            int qrow = wave * 32 + ni * 16 + l16;
            #pragma unroll
            for (int mi = 0; mi < 4; ++mi) {
                float p0 = exp2f(sacc[mi][ni][0] * SC - MST);
                float p1 = exp2f(sacc[mi][ni][1] * SC - MST);
                float p2 = exp2f(sacc[mi][ni][2] * SC - MST);
                float p3 = exp2f(sacc[mi][ni][3] * SC - MST);
                lsum[ni] += (p0 + p1) + (p2 + p3);
                uint2 w; w.x = pack2bf(p0, p1); w.y = pack2bf(p2, p3);
                // 8B write, swizzled: block = 2*mi + (quad>>1), inner = (quad&1)*4 shorts
                *(uint2*)&Ps[qrow * 64 + ((2 * mi + (quad >> 1)) ^ l8) * 8 + (quad & 1) * 4] = w;
            }
        }

        // PV: O[q][d] += P @ V  (Ps rows are wave-private; DS pipe in-order per wave)
        #pragma unroll
        for (int kk = 0; kk < 2; ++kk) {
            short8 pf[2];
            #pragma unroll
            for (int mo = 0; mo < 2; ++mo)
                pf[mo] = *(const short8*)&Ps[(wave * 32 + mo * 16 + l16) * 64 + ((kk * 4 + quad) ^ l8) * 8];
            #pragma unroll
            for (int nd = 0; nd < 4; ++nd) {
                short8 vf = *(const short8*)&Vt[(nd * 16 + l16) * 64 + ((kk * 4 + quad) ^ l8) * 8];
                #pragma unroll
                for (int mo = 0; mo < 2; ++mo)
                    acc_o[mo][nd] = __builtin_amdgcn_mfma_f32_16x16x32_bf16(pf[mo], vf, acc_o[mo][nd], 0, 0, 0);
            }
        }
    }

    // final l reduction across the 4 lanes sharing each q column, then store
    #pragma unroll
    for (int ni = 0; ni < 2; ++ni) {
        lsum[ni] += __shfl_xor(lsum[ni], 16);
        lsum[ni] += __shfl_xor(lsum[ni], 32);
    }
    #pragma unroll
    for (int mo = 0; mo < 2; ++mo)
        #pragma unroll
        for (int rr = 0; rr < 4; ++rr) {
            float lr = __shfl(lsum[mo], quad * 4 + rr, 16);
            float inv = 1.f / lr;
            int qg = q0 + wave * 32 + mo * 16 + quad * 4 + rr;
            size_t base = ((size_t)(b * 2048 + qg)) * 1024 + h * 64;
            #pragma unroll
            for (int nd = 0; nd < 4; ++nd)
                o[base + nd * 16 + l16] = f2bf(acc_o[mo][nd][rr] * inv);
        }
}

// ---------- LayerNorm (row=token, 1024 cols), fp32 in/out ----------
__global__ __launch_bounds__(256) void k_ln(const float* __restrict__ res,
                                            const float* __restrict__ g,
                                            const float* __restrict__ be,
                                            float* __restrict__ out) {
    __shared__ float red[8];
    const int row = blockIdx.x, t = threadIdx.x;
    const float* x = res + (size_t)row * 1024;
    float4 v = *(const float4*)(x + t * 4);
    float s = v.x + v.y + v.z + v.w;
    float sq = v.x * v.x + v.y * v.y + v.z * v.z + v.w * v.w;
    #pragma unroll
    for (int off = 32; off; off >>= 1) { s += __shfl_down(s, off); sq += __shfl_down(sq, off); }
    if ((t & 63) == 0) { red[t >> 6] = s; red[4 + (t >> 6)] = sq; }
    __syncthreads();
    float ts = red[0] + red[1] + red[2] + red[3];
    float tq = red[4] + red[5] + red[6] + red[7];
    float mu = ts * (1.f / 1024.f);
    float var = tq * (1.f / 1024.f) - mu * mu;
    float rstd = rsqrtf(var + 1e-6f);
    float4 gg = *(const float4*)(g + t * 4);
    float4 bb = *(const float4*)(be + t * 4);
    float4 ov;
    ov.x = (v.x - mu) * rstd * gg.x + bb.x;
    ov.y = (v.y - mu) * rstd * gg.y + bb.y;
    ov.z = (v.z - mu) * rstd * gg.z + bb.z;
    ov.w = (v.w - mu) * rstd * gg.w + bb.w;
    *(float4*)(out + (size_t)row * 1024 + t * 4) = ov;
}

// ---------- launch ----------
extern "C" void kernel_launch(void* const* d_in, const int* in_sizes, int n_in,
                              void* d_out, int out_size, void* d_ws, size_t ws_size,
                              hipStream_t stream) {
    (void)in_sizes; (void)n_in; (void)out_size; (void)ws_size;
    const float* y    = (const float*)d_in[0];
    const float* Wqkv = (const float*)d_in[1];
    const float* bqkv = (const float*)d_in[2];
    const float* Wmsa = (const float*)d_in[3];
    const float* Bq = (const float*)d_in[4];
    const float* Aq = (const float*)d_in[5];
    const float* Bk = (const float*)d_in[6];
    const float* Ak = (const float*)d_in[7];
    const float* Bv = (const float*)d_in[8];
    const float* Av = (const float*)d_in[9];
    const float* Bo = (const float*)d_in[10];
    const float* Ao = (const float*)d_in[11];
    const float* gamma = (const float*)d_in[12];
    const float* beta  = (const float*)d_in[13];

    char* ws = (char*)d_ws;
    unsigned short* yb   = (unsigned short*)(ws);               // 8 MB bf16(y); reused as obuf
    unsigned short* weq  = (unsigned short*)(ws + (8u  << 20)); // 6 MB [3072][1024]
    unsigned short* wem  = (unsigned short*)(ws + (14u << 20)); // 2 MB [1024][1024]
    unsigned short* qkv  = (unsigned short*)(ws + (16u << 20)); // 24 MB [4096][3072]; reused as res (fp32 16 MB)
    unsigned short* vtg  = (unsigned short*)(ws + (40u << 20)); // 8 MB [32][64][2048] V^T
    unsigned short* obuf = yb;
    float* res = (float*)qkv;

    k_cvt <<<4096, 256, 0, stream>>>(y, yb);
    k_wqkv<<<12288, 256, 0, stream>>>(Wqkv, Bq, Aq, Bk, Ak, Bv, Av, weq);
    k_wmsa<<<4096, 256, 0, stream>>>(Wmsa, Bo, Ao, wem);
    k_gemm<0><<<dim3(24, 32), 256, 0, stream>>>(yb, weq, bqkv, nullptr, (void*)qkv, 4096, 3072, 1024);
    k_vt  <<<dim3(32, 16, 2), 256, 0, stream>>>(qkv, vtg);
    k_attn<<<dim3(16, 16, 2), 256, 0, stream>>>(qkv, vtg, obuf);
    k_gemm<1><<<dim3(8, 32), 256, 0, stream>>>(obuf, wem, nullptr, y, (void*)res, 4096, 1024, 1024);
    k_ln  <<<4096, 256, 0, stream>>>(res, gamma, beta, (float*)d_out);
}

// Round 5
// 258.873 us; speedup vs baseline: 1.1600x; 1.0405x over previous
//
#include <hip/hip_runtime.h>
#include <hip/hip_bf16.h>
#include <stdint.h>

// ---------- types ----------
typedef __attribute__((ext_vector_type(8))) short short8;   // 8 x bf16 (raw)
typedef __attribute__((ext_vector_type(4))) float f32x4;

typedef const __attribute__((address_space(1))) void gv_t;
typedef __attribute__((address_space(3))) void lv_t;

__device__ __forceinline__ void gl_lds16(const void* g, void* l) {
    // async global->LDS, 16B per lane; LDS dest must be waveBase + lane*16
    __builtin_amdgcn_global_load_lds((gv_t*)g, (lv_t*)l, 16, 0, 0);
}

__device__ __forceinline__ unsigned short f2bf(float f) {
    union { float f; unsigned int u; } v; v.f = f;
    unsigned int r = v.u + 0x7fffu + ((v.u >> 16) & 1u);   // RNE
    return (unsigned short)(r >> 16);
}

__device__ __forceinline__ unsigned int pack2bf(float a, float b) {
    union { __hip_bfloat162 h2; unsigned int u; } cv;
    cv.h2 = __float22bfloat162_rn(make_float2(a, b));   // v_cvt_pk_bf16_f32 on gfx950
    return cv.u;                                        // low = a, high = b
}

__device__ __forceinline__ f32x4 zero4() { f32x4 z = {0.f, 0.f, 0.f, 0.f}; return z; }

// ---------- prep kernels (fp32 inputs -> bf16 working set) ----------
__global__ void k_cvt(const float* __restrict__ y, unsigned short* __restrict__ yb) {
    int i = (blockIdx.x * 256 + threadIdx.x) * 4;
    float4 v = *(const float4*)(y + i);
    union { unsigned short u[4]; uint2 w; } o;
    o.u[0] = f2bf(v.x); o.u[1] = f2bf(v.y); o.u[2] = f2bf(v.z); o.u[3] = f2bf(v.w);
    *(uint2*)(yb + i) = o.w;
}

__global__ void k_wqkv(const float* __restrict__ W,
                       const float* __restrict__ Bq, const float* __restrict__ Aq,
                       const float* __restrict__ Bk, const float* __restrict__ Ak,
                       const float* __restrict__ Bv, const float* __restrict__ Av,
                       unsigned short* __restrict__ out) {
    int idx = blockIdx.x * 256 + threadIdx.x;     // n*1024 + k
    int n = idx >> 10, k = idx & 1023;
    int sel = n >> 10, n0 = n & 1023;
    const float* Bp = (sel == 0) ? Bq : (sel == 1) ? Bk : Bv;
    const float* Ap = (sel == 0) ? Aq : (sel == 1) ? Ak : Av;
    float acc = W[idx];
    #pragma unroll
    for (int r = 0; r < 8; ++r) acc += Bp[k * 8 + r] * Ap[r * 1024 + n0];
    out[idx] = f2bf(acc);
}

__global__ void k_wmsa(const float* __restrict__ W,
                       const float* __restrict__ Bo, const float* __restrict__ Ao,
                       unsigned short* __restrict__ out) {
    int idx = blockIdx.x * 256 + threadIdx.x;     // n*1024 + k
    int n = idx >> 10, k = idx & 1023;
    float acc = W[idx];
    #pragma unroll
    for (int r = 0; r < 8; ++r) acc += Bo[k * 8 + r] * Ao[r * 1024 + n];
    out[idx] = f2bf(acc);
}

// ---------- GEMM: C[M,N] = A[M,K](bf16) @ B[N,K]^T(bf16)  (m97 structure) ----------
template <int EPI>
__global__ __launch_bounds__(256, 2) void k_gemm(const unsigned short* __restrict__ Ag,
                                                 const unsigned short* __restrict__ Bg,
                                                 const float* __restrict__ bias,
                                                 const float* __restrict__ yres,
                                                 void* __restrict__ Cout,
                                                 int M, int N, int K) {
    __shared__ unsigned short As[128 * 32];
    __shared__ unsigned short Bs[128 * 32];
    const int flat = threadIdx.x;
    const int m0 = blockIdx.y * 128, n0 = blockIdx.x * 128;
    const int lane = flat & 63, wave = flat >> 6;
    const int l16 = lane & 15, quad = lane >> 4;
    const int wm = (wave >> 1) * 64, wn = (wave & 1) * 64;

    f32x4 acc[4][4];
    #pragma unroll
    for (int mi = 0; mi < 4; ++mi)
        #pragma unroll
        for (int ni = 0; ni < 4; ++ni) acc[mi][ni] = zero4();

    const unsigned short* ap = Ag + (size_t)(m0 + (flat >> 2)) * K + (flat & 3) * 8;
    const unsigned short* bp = Bg + (size_t)(n0 + (flat >> 2)) * K + (flat & 3) * 8;
    const size_t rstep = (size_t)64 * K;

    for (int k0 = 0; k0 < K; k0 += 32) {
        __syncthreads();
        gl_lds16(ap,         &As[flat * 8]);
        gl_lds16(ap + rstep, &As[2048 + flat * 8]);
        gl_lds16(bp,         &Bs[flat * 8]);
        gl_lds16(bp + rstep, &Bs[2048 + flat * 8]);
        ap += 32; bp += 32;
        __syncthreads();

        short8 af[4], bfr[4];
        #pragma unroll
        for (int i = 0; i < 4; ++i) af[i] = *(const short8*)&As[(wm + i * 16 + l16) * 32 + quad * 8];
        #pragma unroll
        for (int i = 0; i < 4; ++i) bfr[i] = *(const short8*)&Bs[(wn + i * 16 + l16) * 32 + quad * 8];
        #pragma unroll
        for (int mi = 0; mi < 4; ++mi)
            #pragma unroll
            for (int ni = 0; ni < 4; ++ni)
                acc[mi][ni] = __builtin_amdgcn_mfma_f32_16x16x32_bf16(af[mi], bfr[ni], acc[mi][ni], 0, 0, 0);
    }

    // epilogue: C/D layout col=lane&15, row=quad*4+reg
    if (EPI == 0) {
        unsigned short* C = (unsigned short*)Cout;
        #pragma unroll
        for (int ni = 0; ni < 4; ++ni) {
            int col = n0 + wn + ni * 16 + l16;
            float bv = bias[col];
            #pragma unroll
            for (int mi = 0; mi < 4; ++mi) {
                int row = m0 + wm + mi * 16 + quad * 4;
                #pragma unroll
                for (int r = 0; r < 4; ++r)
                    C[(size_t)(row + r) * N + col] = f2bf(acc[mi][ni][r] + bv);
            }
        }
    } else {
        float* C = (float*)Cout;
        #pragma unroll
        for (int ni = 0; ni < 4; ++ni) {
            int col = n0 + wn + ni * 16 + l16;
            #pragma unroll
            for (int mi = 0; mi < 4; ++mi) {
                int row = m0 + wm + mi * 16 + quad * 4;
                #pragma unroll
                for (int r = 0; r < 4; ++r)
                    C[(size_t)(row + r) * N + col] = acc[mi][ni][r] + yres[(size_t)(row + r) * N + col];
            }
        }
    }
}

// ---------- V transpose: qkv V-part -> vtg[b,h][d][k] (k contiguous) ----------
__global__ __launch_bounds__(256) void k_vt(const unsigned short* __restrict__ qkv,
                                            unsigned short* __restrict__ vtg) {
    __shared__ unsigned short T[64 * 72];
    const int t = threadIdx.x;
    const int k0 = blockIdx.x * 64, h = blockIdx.y, b = blockIdx.z;
    const unsigned short* vbase = qkv + (size_t)(b * 2048) * 3072 + 2048 + h * 64;
    #pragma unroll
    for (int i = 0; i < 2; ++i) {
        int B = i * 256 + t;                       // 0..511
        int row = B >> 3, c = B & 7;
        short8 v = *(const short8*)(vbase + (size_t)(k0 + row) * 3072 + c * 8);
        *(short8*)&T[row * 72 + c * 8] = v;
    }
    __syncthreads();
    unsigned short* obase = vtg + ((size_t)((b * 16 + h) * 64)) * 2048 + k0;
    #pragma unroll
    for (int i = 0; i < 2; ++i) {
        int B = i * 256 + t;
        int d = B >> 3, kc = B & 7;
        union { unsigned short u[8]; short8 v; } pk;
        #pragma unroll
        for (int jj = 0; jj < 8; ++jj) pk.u[jj] = T[(kc * 8 + jj) * 72 + d];
        *(short8*)(obase + (size_t)d * 2048 + kc * 8) = pk.v;
    }
}

// ---------- fused flash attention (static-max softmax, swizzled LDS, dbuf prefetch) ----------
// Tiles stored as 64-short rows; 16B chunk c of row r lives at chunk slot c^(r&7).
// K/Vt double-buffered: loads for tile j+1 issued at top of iter j, drained by the
// single end-of-iter barrier => full compute-phase overlap of the global->LDS latency.
__global__ __launch_bounds__(256, 2) void k_attn(const unsigned short* __restrict__ qkv,
                                                 const unsigned short* __restrict__ vtg,
                                                 unsigned short* __restrict__ o) {
    __shared__ unsigned short LDS[24576];          // 48 KB
    unsigned short* Qs = LDS;                      // [128][64] swizzled (aliased by Ps after preload)
    unsigned short* Ps = LDS;                      // [128][64] (rows=q, cols=k) — aliases Qs
    unsigned short* Ks0 = LDS + 8192;              // [2][64][64]
    unsigned short* Vt0 = LDS + 16384;             // [2][64][64]  (rows=d, cols=k)

    const int t = threadIdx.x;
    const int lane = t & 63, wave = t >> 6;
    const int l16 = lane & 15, quad = lane >> 4;
    const int l8 = l16 & 7;
    const int q0 = blockIdx.x * 128;
    const int h = blockIdx.y, b = blockIdx.z;

    const unsigned short* qbase = qkv + (size_t)(b * 2048) * 3072 + h * 64;
    const unsigned short* kbase = qbase + 1024;
    const unsigned short* vtbase = vtg + (size_t)((b * 16 + h) * 64) * 2048;

    // stage Q tile [128][64] swizzled, via global_load_lds
    #pragma unroll
    for (int i = 0; i < 4; ++i) {
        int B = i * 256 + t;                       // 16B-block index 0..1023
        int row = B >> 3, c = (B & 7) ^ (row & 7);
        gl_lds16(qbase + (size_t)(q0 + row) * 3072 + c * 8, &Qs[B * 8]);
    }

    // per-lane staging constants for K / Vt tiles (512 blocks each, 2 calls)
    const int B0 = t, B1 = t + 256;
    const int r0 = B0 >> 3, c0 = (B0 & 7) ^ (r0 & 7);
    const int r1 = B1 >> 3, c1 = (B1 & 7) ^ (r1 & 7);
    const unsigned short* kp0 = kbase + (size_t)r0 * 3072 + c0 * 8;
    const unsigned short* kp1 = kbase + (size_t)r1 * 3072 + c1 * 8;
    const unsigned short* vp0 = vtbase + (size_t)r0 * 2048 + c0 * 8;
    const unsigned short* vp1 = vtbase + (size_t)r1 * 2048 + c1 * 8;

    // prefetch tile 0 into buffer 0
    gl_lds16(kp0, &Ks0[B0 * 8]);
    gl_lds16(kp1, &Ks0[B1 * 8]);
    gl_lds16(vp0, &Vt0[B0 * 8]);
    gl_lds16(vp1, &Vt0[B1 * 8]);
    kp0 += 64 * 3072; kp1 += 64 * 3072; vp0 += 64; vp1 += 64;

    __syncthreads();                               // Q + tile0 staged & visible

    // preload Q B-fragments (loop-invariant): B[n=q][k=d]
    short8 qf[2][2];
    #pragma unroll
    for (int ni = 0; ni < 2; ++ni)
        #pragma unroll
        for (int kk = 0; kk < 2; ++kk)
            qf[ni][kk] = *(const short8*)&Qs[(wave * 32 + ni * 16 + l16) * 64 + ((kk * 4 + quad) ^ l8) * 8];

    __syncthreads();                               // all qf reads done before any Ps write

    f32x4 acc_o[2][4];
    #pragma unroll
    for (int mo = 0; mo < 2; ++mo)
        #pragma unroll
        for (int nd = 0; nd < 4; ++nd) acc_o[mo][nd] = zero4();
    float lsum[2] = {0.f, 0.f};
    const float SC  = 0.18033688011112042f;        // log2(e)/sqrt(64)
    const float MST = 8.0f;                        // static max (cancels exactly; fp32 range safe)

    for (int j = 0; j < 32; ++j) {
        const unsigned short* Ks = Ks0 + (j & 1) * 4096;
        const unsigned short* Vt = Vt0 + (j & 1) * 4096;

        // prefetch tile j+1 into the other buffer (overlaps this iter's compute)
        if (j < 31) {
            unsigned short* Kn = Ks0 + ((j + 1) & 1) * 4096;
            unsigned short* Vn = Vt0 + ((j + 1) & 1) * 4096;
            gl_lds16(kp0, &Kn[B0 * 8]);
            gl_lds16(kp1, &Kn[B1 * 8]);
            gl_lds16(vp0, &Vn[B0 * 8]);
            gl_lds16(vp1, &Vn[B1 * 8]);
            kp0 += 64 * 3072; kp1 += 64 * 3072; vp0 += 64; vp1 += 64;
        }

        // S^T = K @ Q^T : per wave [64 k x 32 q]
        f32x4 sacc[4][2];
        #pragma unroll
        for (int mi = 0; mi < 4; ++mi)
            #pragma unroll
            for (int ni = 0; ni < 2; ++ni) sacc[mi][ni] = zero4();
        #pragma unroll
        for (int kk = 0; kk < 2; ++kk)
            #pragma unroll
            for (int mi = 0; mi < 4; ++mi) {
                short8 kf = *(const short8*)&Ks[(mi * 16 + l16) * 64 + ((kk * 4 + quad) ^ l8) * 8];
                #pragma unroll
                for (int ni = 0; ni < 2; ++ni)
                    sacc[mi][ni] = __builtin_amdgcn_mfma_f32_16x16x32_bf16(kf, qf[ni][kk], sacc[mi][ni], 0, 0, 0);
            }

        // static-max softmax: p = exp2(s*SC - MST); accumulate per-lane partial l
        #pragma unroll
        for (int ni = 0; ni < 2; ++ni) {
            int qrow = wave * 32 + ni * 16 + l16;
            #pragma unroll
            for (int mi = 0; mi < 4; ++mi) {
                float p0 = exp2f(__builtin_fmaf(sacc[mi][ni][0], SC, -MST));
                float p1 = exp2f(__builtin_fmaf(sacc[mi][ni][1], SC, -MST));
                float p2 = exp2f(__builtin_fmaf(sacc[mi][ni][2], SC, -MST));
                float p3 = exp2f(__builtin_fmaf(sacc[mi][ni][3], SC, -MST));
                lsum[ni] += (p0 + p1) + (p2 + p3);
                uint2 w; w.x = pack2bf(p0, p1); w.y = pack2bf(p2, p3);
                // 8B write, swizzled: block = 2*mi + (quad>>1), inner = (quad&1)*4 shorts
                *(uint2*)&Ps[qrow * 64 + ((2 * mi + (quad >> 1)) ^ l8) * 8 + (quad & 1) * 4] = w;
            }
        }

        // PV: O[q][d] += P @ V  (Ps rows are wave-private; DS pipe in-order per wave)
        #pragma unroll
        for (int kk = 0; kk < 2; ++kk) {
            short8 pf[2];
            #pragma unroll
            for (int mo = 0; mo < 2; ++mo)
                pf[mo] = *(const short8*)&Ps[(wave * 32 + mo * 16 + l16) * 64 + ((kk * 4 + quad) ^ l8) * 8];
            #pragma unroll
            for (int nd = 0; nd < 4; ++nd) {
                short8 vf = *(const short8*)&Vt[(nd * 16 + l16) * 64 + ((kk * 4 + quad) ^ l8) * 8];
                #pragma unroll
                for (int mo = 0; mo < 2; ++mo)
                    acc_o[mo][nd] = __builtin_amdgcn_mfma_f32_16x16x32_bf16(pf[mo], vf, acc_o[mo][nd], 0, 0, 0);
            }
        }

        __syncthreads();   // cur-tile reads done everywhere; drains prefetch (issued ~full iter ago)
    }

    // final l reduction across the 4 lanes sharing each q column, then store
    #pragma unroll
    for (int ni = 0; ni < 2; ++ni) {
        lsum[ni] += __shfl_xor(lsum[ni], 16);
        lsum[ni] += __shfl_xor(lsum[ni], 32);
    }
    #pragma unroll
    for (int mo = 0; mo < 2; ++mo)
        #pragma unroll
        for (int rr = 0; rr < 4; ++rr) {
            float lr = __shfl(lsum[mo], quad * 4 + rr, 16);
            float inv = 1.f / lr;
            int qg = q0 + wave * 32 + mo * 16 + quad * 4 + rr;
            size_t base = ((size_t)(b * 2048 + qg)) * 1024 + h * 64;
            #pragma unroll
            for (int nd = 0; nd < 4; ++nd)
                o[base + nd * 16 + l16] = f2bf(acc_o[mo][nd][rr] * inv);
        }
}

// ---------- LayerNorm (row=token, 1024 cols), fp32 in/out ----------
__global__ __launch_bounds__(256) void k_ln(const float* __restrict__ res,
                                            const float* __restrict__ g,
                                            const float* __restrict__ be,
                                            float* __restrict__ out) {
    __shared__ float red[8];
    const int row = blockIdx.x, t = threadIdx.x;
    const float* x = res + (size_t)row * 1024;
    float4 v = *(const float4*)(x + t * 4);
    float s = v.x + v.y + v.z + v.w;
    float sq = v.x * v.x + v.y * v.y + v.z * v.z + v.w * v.w;
    #pragma unroll
    for (int off = 32; off; off >>= 1) { s += __shfl_down(s, off); sq += __shfl_down(sq, off); }
    if ((t & 63) == 0) { red[t >> 6] = s; red[4 + (t >> 6)] = sq; }
    __syncthreads();
    float ts = red[0] + red[1] + red[2] + red[3];
    float tq = red[4] + red[5] + red[6] + red[7];
    float mu = ts * (1.f / 1024.f);
    float var = tq * (1.f / 1024.f) - mu * mu;
    float rstd = rsqrtf(var + 1e-6f);
    float4 gg = *(const float4*)(g + t * 4);
    float4 bb = *(const float4*)(be + t * 4);
    float4 ov;
    ov.x = (v.x - mu) * rstd * gg.x + bb.x;
    ov.y = (v.y - mu) * rstd * gg.y + bb.y;
    ov.z = (v.z - mu) * rstd * gg.z + bb.z;
    ov.w = (v.w - mu) * rstd * gg.w + bb.w;
    *(float4*)(out + (size_t)row * 1024 + t * 4) = ov;
}

// ---------- launch ----------
extern "C" void kernel_launch(void* const* d_in, const int* in_sizes, int n_in,
                              void* d_out, int out_size, void* d_ws, size_t ws_size,
                              hipStream_t stream) {
    (void)in_sizes; (void)n_in; (void)out_size; (void)ws_size;
    const float* y    = (const float*)d_in[0];
    const float* Wqkv = (const float*)d_in[1];
    const float* bqkv = (const float*)d_in[2];
    const float* Wmsa = (const float*)d_in[3];
    const float* Bq = (const float*)d_in[4];
    const float* Aq = (const float*)d_in[5];
    const float* Bk = (const float*)d_in[6];
    const float* Ak = (const float*)d_in[7];
    const float* Bv = (const float*)d_in[8];
    const float* Av = (const float*)d_in[9];
    const float* Bo = (const float*)d_in[10];
    const float* Ao = (const float*)d_in[11];
    const float* gamma = (const float*)d_in[12];
    const float* beta  = (const float*)d_in[13];

    char* ws = (char*)d_ws;
    unsigned short* yb   = (unsigned short*)(ws);               // 8 MB bf16(y); reused as obuf
    unsigned short* weq  = (unsigned short*)(ws + (8u  << 20)); // 6 MB [3072][1024]
    unsigned short* wem  = (unsigned short*)(ws + (14u << 20)); // 2 MB [1024][1024]
    unsigned short* qkv  = (unsigned short*)(ws + (16u << 20)); // 24 MB [4096][3072]; reused as res (fp32 16 MB)
    unsigned short* vtg  = (unsigned short*)(ws + (40u << 20)); // 8 MB [32][64][2048] V^T
    unsigned short* obuf = yb;
    float* res = (float*)qkv;

    k_cvt <<<4096, 256, 0, stream>>>(y, yb);
    k_wqkv<<<12288, 256, 0, stream>>>(Wqkv, Bq, Aq, Bk, Ak, Bv, Av, weq);
    k_wmsa<<<4096, 256, 0, stream>>>(Wmsa, Bo, Ao, wem);
    k_gemm<0><<<dim3(24, 32), 256, 0, stream>>>(yb, weq, bqkv, nullptr, (void*)qkv, 4096, 3072, 1024);
    k_vt  <<<dim3(32, 16, 2), 256, 0, stream>>>(qkv, vtg);
    k_attn<<<dim3(16, 16, 2), 256, 0, stream>>>(qkv, vtg, obuf);
    k_gemm<1><<<dim3(8, 32), 256, 0, stream>>>(obuf, wem, nullptr, y, (void*)res, 4096, 1024, 1024);
    k_ln  <<<4096, 256, 0, stream>>>(res, gamma, beta, (float*)d_out);
}

// Round 6
// 240.996 us; speedup vs baseline: 1.2461x; 1.0742x over previous
//
#include <hip/hip_runtime.h>
#include <hip/hip_bf16.h>
#include <stdint.h>

// ---------- types ----------
typedef __attribute__((ext_vector_type(8))) short short8;   // 8 x bf16 (raw)
typedef __attribute__((ext_vector_type(4))) float f32x4;

typedef const __attribute__((address_space(1))) void gv_t;
typedef __attribute__((address_space(3))) void lv_t;

#define SCQ 0.18033688011112042f   // log2(e)/sqrt(64), folded into Q projection

__device__ __forceinline__ void gl_lds16(const void* g, void* l) {
    // async global->LDS, 16B per lane; LDS dest must be waveBase + lane*16
    __builtin_amdgcn_global_load_lds((gv_t*)g, (lv_t*)l, 16, 0, 0);
}

__device__ __forceinline__ unsigned short f2bf(float f) {
    union { float f; unsigned int u; } v; v.f = f;
    unsigned int r = v.u + 0x7fffu + ((v.u >> 16) & 1u);   // RNE
    return (unsigned short)(r >> 16);
}

__device__ __forceinline__ unsigned int pack2bf(float a, float b) {
    union { __hip_bfloat162 h2; unsigned int u; } cv;
    cv.h2 = __float22bfloat162_rn(make_float2(a, b));   // v_cvt_pk_bf16_f32 on gfx950
    return cv.u;                                        // low = a, high = b
}

__device__ __forceinline__ f32x4 zero4() { f32x4 z = {0.f, 0.f, 0.f, 0.f}; return z; }

// ---------- prep kernels (fp32 inputs -> bf16 working set) ----------
__global__ void k_cvt(const float* __restrict__ y, unsigned short* __restrict__ yb) {
    int i = (blockIdx.x * 256 + threadIdx.x) * 4;
    float4 v = *(const float4*)(y + i);
    union { unsigned short u[4]; uint2 w; } o;
    o.u[0] = f2bf(v.x); o.u[1] = f2bf(v.y); o.u[2] = f2bf(v.z); o.u[3] = f2bf(v.w);
    *(uint2*)(yb + i) = o.w;
}

__global__ void k_wqkv(const float* __restrict__ W,
                       const float* __restrict__ Bq, const float* __restrict__ Aq,
                       const float* __restrict__ Bk, const float* __restrict__ Ak,
                       const float* __restrict__ Bv, const float* __restrict__ Av,
                       unsigned short* __restrict__ out) {
    int idx = blockIdx.x * 256 + threadIdx.x;     // n*1024 + k
    int n = idx >> 10, k = idx & 1023;
    int sel = n >> 10, n0 = n & 1023;
    const float* Bp = (sel == 0) ? Bq : (sel == 1) ? Bk : Bv;
    const float* Ap = (sel == 0) ? Aq : (sel == 1) ? Ak : Av;
    float acc = W[idx];
    #pragma unroll
    for (int r = 0; r < 8; ++r) acc += Bp[k * 8 + r] * Ap[r * 1024 + n0];
    // fold softmax scale*log2(e) into the Q rows
    out[idx] = f2bf(acc * ((sel == 0) ? SCQ : 1.0f));
}

__global__ void k_wmsa(const float* __restrict__ W,
                       const float* __restrict__ Bo, const float* __restrict__ Ao,
                       unsigned short* __restrict__ out) {
    int idx = blockIdx.x * 256 + threadIdx.x;     // n*1024 + k
    int n = idx >> 10, k = idx & 1023;
    float acc = W[idx];
    #pragma unroll
    for (int r = 0; r < 8; ++r) acc += Bo[k * 8 + r] * Ao[r * 1024 + n];
    out[idx] = f2bf(acc);
}

// ---------- GEMM: C[M,N] = A[M,K](bf16) @ B[N,K]^T(bf16), dbuf cross-barrier prefetch ----------
// TM: block m-tile (64 or 128); block n-tile fixed 128. 4 waves: (TM/64) x (256/TM) grid of
// 64 x (TM/2) per-wave tiles. EPI=0: bf16(acc+bias[col]) with Q-scale on col<1024;
// EPI=1: fp32(acc + yres).
template <int TM, int EPI>
__global__ __launch_bounds__(256, 2) void k_gemm(const unsigned short* __restrict__ Ag,
                                                 const unsigned short* __restrict__ Bg,
                                                 const float* __restrict__ bias,
                                                 const float* __restrict__ yres,
                                                 void* __restrict__ Cout,
                                                 int M, int N, int K) {
    constexpr int WAVES_N = 256 / TM;      // 2 (TM=128) or 4 (TM=64)
    constexpr int WN = TM / 2;             // 64 or 32
    constexpr int NI = WN / 16;            // 4 or 2
    constexpr int ACALLS = TM / 64;        // 2 or 1
    __shared__ unsigned short As[2][TM * 32];
    __shared__ unsigned short Bs[2][128 * 32];
    const int flat = threadIdx.x;
    const int m0 = blockIdx.y * TM, n0 = blockIdx.x * 128;
    const int lane = flat & 63, wave = flat >> 6;
    const int l16 = lane & 15, quad = lane >> 4;
    const int wm = (wave / WAVES_N) * 64, wn = (wave % WAVES_N) * WN;

    f32x4 acc[4][NI];
    #pragma unroll
    for (int mi = 0; mi < 4; ++mi)
        #pragma unroll
        for (int ni = 0; ni < NI; ++ni) acc[mi][ni] = zero4();

    const unsigned short* ap = Ag + (size_t)(m0 + (flat >> 2)) * K + (flat & 3) * 8;
    const unsigned short* bp = Bg + (size_t)(n0 + (flat >> 2)) * K + (flat & 3) * 8;
    const size_t rstep = (size_t)64 * K;

    // prefetch k-tile 0 into buffer 0
    #pragma unroll
    for (int c = 0; c < ACALLS; ++c) gl_lds16(ap + c * rstep, &As[0][c * 2048 + flat * 8]);
    gl_lds16(bp,         &Bs[0][flat * 8]);
    gl_lds16(bp + rstep, &Bs[0][2048 + flat * 8]);
    ap += 32; bp += 32;
    __syncthreads();

    for (int k0 = 0; k0 < K; k0 += 32) {
        const int cur = (k0 >> 5) & 1;
        if (k0 + 32 < K) {                 // prefetch next tile into other buffer
            const int nxt = cur ^ 1;
            #pragma unroll
            for (int c = 0; c < ACALLS; ++c) gl_lds16(ap + c * rstep, &As[nxt][c * 2048 + flat * 8]);
            gl_lds16(bp,         &Bs[nxt][flat * 8]);
            gl_lds16(bp + rstep, &Bs[nxt][2048 + flat * 8]);
            ap += 32; bp += 32;
        }

        short8 af[4], bfr[NI];
        #pragma unroll
        for (int i = 0; i < 4; ++i) af[i] = *(const short8*)&As[cur][(wm + i * 16 + l16) * 32 + quad * 8];
        #pragma unroll
        for (int i = 0; i < NI; ++i) bfr[i] = *(const short8*)&Bs[cur][(wn + i * 16 + l16) * 32 + quad * 8];
        #pragma unroll
        for (int mi = 0; mi < 4; ++mi)
            #pragma unroll
            for (int ni = 0; ni < NI; ++ni)
                acc[mi][ni] = __builtin_amdgcn_mfma_f32_16x16x32_bf16(af[mi], bfr[ni], acc[mi][ni], 0, 0, 0);

        __syncthreads();   // cur reads done everywhere; drains prefetch (issued a full iter ago)
    }

    // epilogue: C/D layout col=lane&15, row=quad*4+reg
    if (EPI == 0) {
        unsigned short* C = (unsigned short*)Cout;
        #pragma unroll
        for (int ni = 0; ni < NI; ++ni) {
            int col = n0 + wn + ni * 16 + l16;
            float bv = bias[col] * ((col < 1024) ? SCQ : 1.0f);
            #pragma unroll
            for (int mi = 0; mi < 4; ++mi) {
                int row = m0 + wm + mi * 16 + quad * 4;
                #pragma unroll
                for (int r = 0; r < 4; ++r)
                    C[(size_t)(row + r) * N + col] = f2bf(acc[mi][ni][r] + bv);
            }
        }
    } else {
        float* C = (float*)Cout;
        #pragma unroll
        for (int ni = 0; ni < NI; ++ni) {
            int col = n0 + wn + ni * 16 + l16;
            #pragma unroll
            for (int mi = 0; mi < 4; ++mi) {
                int row = m0 + wm + mi * 16 + quad * 4;
                #pragma unroll
                for (int r = 0; r < 4; ++r)
                    C[(size_t)(row + r) * N + col] = acc[mi][ni][r] + yres[(size_t)(row + r) * N + col];
            }
        }
    }
}

// ---------- V transpose: qkv V-part -> vtg[b,h][d][k] (k contiguous) ----------
__global__ __launch_bounds__(256) void k_vt(const unsigned short* __restrict__ qkv,
                                            unsigned short* __restrict__ vtg) {
    __shared__ unsigned short T[64 * 72];
    const int t = threadIdx.x;
    const int k0 = blockIdx.x * 64, h = blockIdx.y, b = blockIdx.z;
    const unsigned short* vbase = qkv + (size_t)(b * 2048) * 3072 + 2048 + h * 64;
    #pragma unroll
    for (int i = 0; i < 2; ++i) {
        int B = i * 256 + t;                       // 0..511
        int row = B >> 3, c = B & 7;
        short8 v = *(const short8*)(vbase + (size_t)(k0 + row) * 3072 + c * 8);
        *(short8*)&T[row * 72 + c * 8] = v;
    }
    __syncthreads();
    unsigned short* obase = vtg + ((size_t)((b * 16 + h) * 64)) * 2048 + k0;
    #pragma unroll
    for (int i = 0; i < 2; ++i) {
        int B = i * 256 + t;
        int d = B >> 3, kc = B & 7;
        union { unsigned short u[8]; short8 v; } pk;
        #pragma unroll
        for (int jj = 0; jj < 8; ++jj) pk.u[jj] = T[(kc * 8 + jj) * 72 + d];
        *(short8*)(obase + (size_t)d * 2048 + kc * 8) = pk.v;
    }
}

// ---------- fused flash attention (scale pre-folded, swizzled LDS, dbuf prefetch) ----------
// Q rows were pre-scaled by log2(e)/sqrt(64), so p = exp2(sacc) directly (shift-invariant
// softmax, no max needed: |sacc| <~ 6 so exp2 is well within fp32/bf16 range).
__global__ __launch_bounds__(256, 2) void k_attn(const unsigned short* __restrict__ qkv,
                                                 const unsigned short* __restrict__ vtg,
                                                 unsigned short* __restrict__ o) {
    __shared__ unsigned short LDS[24576];          // 48 KB
    unsigned short* Qs = LDS;                      // [128][64] swizzled (aliased by Ps after preload)
    unsigned short* Ps = LDS;                      // [128][64] (rows=q, cols=k) — aliases Qs
    unsigned short* Ks0 = LDS + 8192;              // [2][64][64]
    unsigned short* Vt0 = LDS + 16384;             // [2][64][64]  (rows=d, cols=k)

    const int t = threadIdx.x;
    const int lane = t & 63, wave = t >> 6;
    const int l16 = lane & 15, quad = lane >> 4;
    const int l8 = l16 & 7;
    const int q0 = blockIdx.x * 128;
    const int h = blockIdx.y, b = blockIdx.z;

    const unsigned short* qbase = qkv + (size_t)(b * 2048) * 3072 + h * 64;
    const unsigned short* kbase = qbase + 1024;
    const unsigned short* vtbase = vtg + (size_t)((b * 16 + h) * 64) * 2048;

    // stage Q tile [128][64] swizzled, via global_load_lds
    #pragma unroll
    for (int i = 0; i < 4; ++i) {
        int B = i * 256 + t;                       // 16B-block index 0..1023
        int row = B >> 3, c = (B & 7) ^ (row & 7);
        gl_lds16(qbase + (size_t)(q0 + row) * 3072 + c * 8, &Qs[B * 8]);
    }

    // per-lane staging constants for K / Vt tiles (512 blocks each, 2 calls)
    const int B0 = t, B1 = t + 256;
    const int r0 = B0 >> 3, c0 = (B0 & 7) ^ (r0 & 7);
    const int r1 = B1 >> 3, c1 = (B1 & 7) ^ (r1 & 7);
    const unsigned short* kp0 = kbase + (size_t)r0 * 3072 + c0 * 8;
    const unsigned short* kp1 = kbase + (size_t)r1 * 3072 + c1 * 8;
    const unsigned short* vp0 = vtbase + (size_t)r0 * 2048 + c0 * 8;
    const unsigned short* vp1 = vtbase + (size_t)r1 * 2048 + c1 * 8;

    // prefetch tile 0 into buffer 0
    gl_lds16(kp0, &Ks0[B0 * 8]);
    gl_lds16(kp1, &Ks0[B1 * 8]);
    gl_lds16(vp0, &Vt0[B0 * 8]);
    gl_lds16(vp1, &Vt0[B1 * 8]);
    kp0 += 64 * 3072; kp1 += 64 * 3072; vp0 += 64; vp1 += 64;

    __syncthreads();                               // Q + tile0 staged & visible

    // preload Q B-fragments (loop-invariant): B[n=q][k=d]
    short8 qf[2][2];
    #pragma unroll
    for (int ni = 0; ni < 2; ++ni)
        #pragma unroll
        for (int kk = 0; kk < 2; ++kk)
            qf[ni][kk] = *(const short8*)&Qs[(wave * 32 + ni * 16 + l16) * 64 + ((kk * 4 + quad) ^ l8) * 8];

    __syncthreads();                               // all qf reads done before any Ps write

    f32x4 acc_o[2][4];
    #pragma unroll
    for (int mo = 0; mo < 2; ++mo)
        #pragma unroll
        for (int nd = 0; nd < 4; ++nd) acc_o[mo][nd] = zero4();
    float lsum[2] = {0.f, 0.f};

    for (int j = 0; j < 32; ++j) {
        const unsigned short* Ks = Ks0 + (j & 1) * 4096;
        const unsigned short* Vt = Vt0 + (j & 1) * 4096;

        // prefetch tile j+1 into the other buffer (overlaps this iter's compute)
        if (j < 31) {
            unsigned short* Kn = Ks0 + ((j + 1) & 1) * 4096;
            unsigned short* Vn = Vt0 + ((j + 1) & 1) * 4096;
            gl_lds16(kp0, &Kn[B0 * 8]);
            gl_lds16(kp1, &Kn[B1 * 8]);
            gl_lds16(vp0, &Vn[B0 * 8]);
            gl_lds16(vp1, &Vn[B1 * 8]);
            kp0 += 64 * 3072; kp1 += 64 * 3072; vp0 += 64; vp1 += 64;
        }

        // S^T = K @ Q^T : per wave [64 k x 32 q]
        f32x4 sacc[4][2];
        #pragma unroll
        for (int mi = 0; mi < 4; ++mi)
            #pragma unroll
            for (int ni = 0; ni < 2; ++ni) sacc[mi][ni] = zero4();
        #pragma unroll
        for (int kk = 0; kk < 2; ++kk)
            #pragma unroll
            for (int mi = 0; mi < 4; ++mi) {
                short8 kf = *(const short8*)&Ks[(mi * 16 + l16) * 64 + ((kk * 4 + quad) ^ l8) * 8];
                #pragma unroll
                for (int ni = 0; ni < 2; ++ni)
                    sacc[mi][ni] = __builtin_amdgcn_mfma_f32_16x16x32_bf16(kf, qf[ni][kk], sacc[mi][ni], 0, 0, 0);
            }

        // softmax numerator: p = exp2(sacc) (scale pre-folded into Q, shift-free)
        #pragma unroll
        for (int ni = 0; ni < 2; ++ni) {
            int qrow = wave * 32 + ni * 16 + l16;
            #pragma unroll
            for (int mi = 0; mi < 4; ++mi) {
                float p0 = exp2f(sacc[mi][ni][0]);
                float p1 = exp2f(sacc[mi][ni][1]);
                float p2 = exp2f(sacc[mi][ni][2]);
                float p3 = exp2f(sacc[mi][ni][3]);
                lsum[ni] += (p0 + p1) + (p2 + p3);
                uint2 w; w.x = pack2bf(p0, p1); w.y = pack2bf(p2, p3);
                // 8B write, swizzled: block = 2*mi + (quad>>1), inner = (quad&1)*4 shorts
                *(uint2*)&Ps[qrow * 64 + ((2 * mi + (quad >> 1)) ^ l8) * 8 + (quad & 1) * 4] = w;
            }
        }

        // PV: O[q][d] += P @ V  (Ps rows are wave-private; DS pipe in-order per wave)
        #pragma unroll
        for (int kk = 0; kk < 2; ++kk) {
            short8 pf[2];
            #pragma unroll
            for (int mo = 0; mo < 2; ++mo)
                pf[mo] = *(const short8*)&Ps[(wave * 32 + mo * 16 + l16) * 64 + ((kk * 4 + quad) ^ l8) * 8];
            #pragma unroll
            for (int nd = 0; nd < 4; ++nd) {
                short8 vf = *(const short8*)&Vt[(nd * 16 + l16) * 64 + ((kk * 4 + quad) ^ l8) * 8];
                #pragma unroll
                for (int mo = 0; mo < 2; ++mo)
                    acc_o[mo][nd] = __builtin_amdgcn_mfma_f32_16x16x32_bf16(pf[mo], vf, acc_o[mo][nd], 0, 0, 0);
            }
        }

        __syncthreads();   // cur-tile reads done everywhere; drains prefetch (issued ~full iter ago)
    }

    // final l reduction across the 4 lanes sharing each q column, then store
    #pragma unroll
    for (int ni = 0; ni < 2; ++ni) {
        lsum[ni] += __shfl_xor(lsum[ni], 16);
        lsum[ni] += __shfl_xor(lsum[ni], 32);
    }
    #pragma unroll
    for (int mo = 0; mo < 2; ++mo)
        #pragma unroll
        for (int rr = 0; rr < 4; ++rr) {
            float lr = __shfl(lsum[mo], quad * 4 + rr, 16);
            float inv = 1.f / lr;
            int qg = q0 + wave * 32 + mo * 16 + quad * 4 + rr;
            size_t base = ((size_t)(b * 2048 + qg)) * 1024 + h * 64;
            #pragma unroll
            for (int nd = 0; nd < 4; ++nd)
                o[base + nd * 16 + l16] = f2bf(acc_o[mo][nd][rr] * inv);
        }
}

// ---------- LayerNorm (row=token, 1024 cols), fp32 in/out ----------
__global__ __launch_bounds__(256) void k_ln(const float* __restrict__ res,
                                            const float* __restrict__ g,
                                            const float* __restrict__ be,
                                            float* __restrict__ out) {
    __shared__ float red[8];
    const int row = blockIdx.x, t = threadIdx.x;
    const float* x = res + (size_t)row * 1024;
    float4 v = *(const float4*)(x + t * 4);
    float s = v.x + v.y + v.z + v.w;
    float sq = v.x * v.x + v.y * v.y + v.z * v.z + v.w * v.w;
    #pragma unroll
    for (int off = 32; off; off >>= 1) { s += __shfl_down(s, off); sq += __shfl_down(sq, off); }
    if ((t & 63) == 0) { red[t >> 6] = s; red[4 + (t >> 6)] = sq; }
    __syncthreads();
    float ts = red[0] + red[1] + red[2] + red[3];
    float tq = red[4] + red[5] + red[6] + red[7];
    float mu = ts * (1.f / 1024.f);
    float var = tq * (1.f / 1024.f) - mu * mu;
    float rstd = rsqrtf(var + 1e-6f);
    float4 gg = *(const float4*)(g + t * 4);
    float4 bb = *(const float4*)(be + t * 4);
    float4 ov;
    ov.x = (v.x - mu) * rstd * gg.x + bb.x;
    ov.y = (v.y - mu) * rstd * gg.y + bb.y;
    ov.z = (v.z - mu) * rstd * gg.z + bb.z;
    ov.w = (v.w - mu) * rstd * gg.w + bb.w;
    *(float4*)(out + (size_t)row * 1024 + t * 4) = ov;
}

// ---------- launch ----------
extern "C" void kernel_launch(void* const* d_in, const int* in_sizes, int n_in,
                              void* d_out, int out_size, void* d_ws, size_t ws_size,
                              hipStream_t stream) {
    (void)in_sizes; (void)n_in; (void)out_size; (void)ws_size;
    const float* y    = (const float*)d_in[0];
    const float* Wqkv = (const float*)d_in[1];
    const float* bqkv = (const float*)d_in[2];
    const float* Wmsa = (const float*)d_in[3];
    const float* Bq = (const float*)d_in[4];
    const float* Aq = (const float*)d_in[5];
    const float* Bk = (const float*)d_in[6];
    const float* Ak = (const float*)d_in[7];
    const float* Bv = (const float*)d_in[8];
    const float* Av = (const float*)d_in[9];
    const float* Bo = (const float*)d_in[10];
    const float* Ao = (const float*)d_in[11];
    const float* gamma = (const float*)d_in[12];
    const float* beta  = (const float*)d_in[13];

    char* ws = (char*)d_ws;
    unsigned short* yb   = (unsigned short*)(ws);               // 8 MB bf16(y); reused as obuf
    unsigned short* weq  = (unsigned short*)(ws + (8u  << 20)); // 6 MB [3072][1024]
    unsigned short* wem  = (unsigned short*)(ws + (14u << 20)); // 2 MB [1024][1024]
    unsigned short* qkv  = (unsigned short*)(ws + (16u << 20)); // 24 MB [4096][3072]; reused as res (fp32 16 MB)
    unsigned short* vtg  = (unsigned short*)(ws + (40u << 20)); // 8 MB [32][64][2048] V^T
    unsigned short* obuf = yb;
    float* res = (float*)qkv;

    k_cvt <<<4096, 256, 0, stream>>>(y, yb);
    k_wqkv<<<12288, 256, 0, stream>>>(Wqkv, Bq, Aq, Bk, Ak, Bv, Av, weq);
    k_wmsa<<<4096, 256, 0, stream>>>(Wmsa, Bo, Ao, wem);
    k_gemm<128, 0><<<dim3(24, 32), 256, 0, stream>>>(yb, weq, bqkv, nullptr, (void*)qkv, 4096, 3072, 1024);
    k_vt  <<<dim3(32, 16, 2), 256, 0, stream>>>(qkv, vtg);
    k_attn<<<dim3(16, 16, 2), 256, 0, stream>>>(qkv, vtg, obuf);
    k_gemm<64, 1><<<dim3(8, 64), 256, 0, stream>>>(obuf, wem, nullptr, y, (void*)res, 4096, 1024, 1024);
    k_ln  <<<4096, 256, 0, stream>>>(res, gamma, beta, (float*)d_out);
}

// Round 7
// 220.744 us; speedup vs baseline: 1.3604x; 1.0917x over previous
//
#include <hip/hip_runtime.h>
#include <hip/hip_bf16.h>
#include <stdint.h>

// ---------- types ----------
typedef __attribute__((ext_vector_type(8))) short short8;   // 8 x bf16 (raw)
typedef __attribute__((ext_vector_type(4))) float f32x4;

typedef const __attribute__((address_space(1))) void gv_t;
typedef __attribute__((address_space(3))) void lv_t;

#define SCQ 0.18033688011112042f   // log2(e)/sqrt(64), folded into Q projection

__device__ __forceinline__ void gl_lds16(const void* g, void* l) {
    // async global->LDS, 16B per lane; LDS dest must be waveBase + lane*16
    __builtin_amdgcn_global_load_lds((gv_t*)g, (lv_t*)l, 16, 0, 0);
}

__device__ __forceinline__ unsigned short f2bf(float f) {
    union { float f; unsigned int u; } v; v.f = f;
    unsigned int r = v.u + 0x7fffu + ((v.u >> 16) & 1u);   // RNE
    return (unsigned short)(r >> 16);
}

__device__ __forceinline__ unsigned int pack2bf(float a, float b) {
    union { __hip_bfloat162 h2; unsigned int u; } cv;
    cv.h2 = __float22bfloat162_rn(make_float2(a, b));   // v_cvt_pk_bf16_f32 on gfx950
    return cv.u;                                        // low = a, high = b
}

__device__ __forceinline__ f32x4 zero4() { f32x4 z = {0.f, 0.f, 0.f, 0.f}; return z; }

// ---------- fused prep: LoRA weight fold (Wqkv & Wmsa) + y->bf16 cvt ----------
// wout = weq (3M elems) immediately followed by wem (1M) in the workspace.
__global__ void k_prep(const float* __restrict__ y,
                       const float* __restrict__ Wqkv, const float* __restrict__ Wmsa,
                       const float* __restrict__ Bq, const float* __restrict__ Aq,
                       const float* __restrict__ Bk, const float* __restrict__ Ak,
                       const float* __restrict__ Bv, const float* __restrict__ Av,
                       const float* __restrict__ Bo, const float* __restrict__ Ao,
                       unsigned short* __restrict__ wout, unsigned short* __restrict__ yb) {
    const int bid = blockIdx.x;
    if (bid < 16384) {
        int idx = bid * 256 + threadIdx.x;     // n*1024 + k, n in [0,4096)
        int n = idx >> 10, k = idx & 1023;
        int sel = n >> 10, n0 = n & 1023;
        const float* Bp = (sel == 0) ? Bq : (sel == 1) ? Bk : (sel == 2) ? Bv : Bo;
        const float* Ap = (sel == 0) ? Aq : (sel == 1) ? Ak : (sel == 2) ? Av : Ao;
        float acc = (sel < 3) ? Wqkv[idx] : Wmsa[idx - 3145728];
        #pragma unroll
        for (int r = 0; r < 8; ++r) acc += Bp[k * 8 + r] * Ap[r * 1024 + n0];
        wout[idx] = f2bf(acc * ((sel == 0) ? SCQ : 1.0f));
    } else {
        int i = ((bid - 16384) * 256 + threadIdx.x) * 4;
        float4 v = *(const float4*)(y + i);
        union { unsigned short u[4]; uint2 w; } o;
        o.u[0] = f2bf(v.x); o.u[1] = f2bf(v.y); o.u[2] = f2bf(v.z); o.u[3] = f2bf(v.w);
        *(uint2*)(yb + i) = o.w;
    }
}

// ---------- GEMM: C[M,N] = A[M,K](bf16) @ B[N,K]^T(bf16), dbuf cross-barrier prefetch ----------
template <int TM, int EPI, int MINW>
__global__ __launch_bounds__(256, MINW) void k_gemm(const unsigned short* __restrict__ Ag,
                                                    const unsigned short* __restrict__ Bg,
                                                    const float* __restrict__ bias,
                                                    const float* __restrict__ yres,
                                                    void* __restrict__ Cout,
                                                    int M, int N, int K) {
    constexpr int WAVES_N = 256 / TM;
    constexpr int WN = TM / 2;
    constexpr int NI = WN / 16;
    constexpr int ACALLS = TM / 64;
    __shared__ unsigned short As[2][TM * 32];
    __shared__ unsigned short Bs[2][128 * 32];
    const int flat = threadIdx.x;
    const int m0 = blockIdx.y * TM, n0 = blockIdx.x * 128;
    const int lane = flat & 63, wave = flat >> 6;
    const int l16 = lane & 15, quad = lane >> 4;
    const int wm = (wave / WAVES_N) * 64, wn = (wave % WAVES_N) * WN;

    f32x4 acc[4][NI];
    #pragma unroll
    for (int mi = 0; mi < 4; ++mi)
        #pragma unroll
        for (int ni = 0; ni < NI; ++ni) acc[mi][ni] = zero4();

    const unsigned short* ap = Ag + (size_t)(m0 + (flat >> 2)) * K + (flat & 3) * 8;
    const unsigned short* bp = Bg + (size_t)(n0 + (flat >> 2)) * K + (flat & 3) * 8;
    const size_t rstep = (size_t)64 * K;

    #pragma unroll
    for (int c = 0; c < ACALLS; ++c) gl_lds16(ap + c * rstep, &As[0][c * 2048 + flat * 8]);
    gl_lds16(bp,         &Bs[0][flat * 8]);
    gl_lds16(bp + rstep, &Bs[0][2048 + flat * 8]);
    ap += 32; bp += 32;
    __syncthreads();

    for (int k0 = 0; k0 < K; k0 += 32) {
        const int cur = (k0 >> 5) & 1;
        if (k0 + 32 < K) {
            const int nxt = cur ^ 1;
            #pragma unroll
            for (int c = 0; c < ACALLS; ++c) gl_lds16(ap + c * rstep, &As[nxt][c * 2048 + flat * 8]);
            gl_lds16(bp,         &Bs[nxt][flat * 8]);
            gl_lds16(bp + rstep, &Bs[nxt][2048 + flat * 8]);
            ap += 32; bp += 32;
        }

        short8 af[4], bfr[NI];
        #pragma unroll
        for (int i = 0; i < 4; ++i) af[i] = *(const short8*)&As[cur][(wm + i * 16 + l16) * 32 + quad * 8];
        #pragma unroll
        for (int i = 0; i < NI; ++i) bfr[i] = *(const short8*)&Bs[cur][(wn + i * 16 + l16) * 32 + quad * 8];
        #pragma unroll
        for (int mi = 0; mi < 4; ++mi)
            #pragma unroll
            for (int ni = 0; ni < NI; ++ni)
                acc[mi][ni] = __builtin_amdgcn_mfma_f32_16x16x32_bf16(af[mi], bfr[ni], acc[mi][ni], 0, 0, 0);

        __syncthreads();
    }

    // epilogue: C/D layout col=lane&15, row=quad*4+reg
    if (EPI == 0) {
        unsigned short* C = (unsigned short*)Cout;
        #pragma unroll
        for (int ni = 0; ni < NI; ++ni) {
            int col = n0 + wn + ni * 16 + l16;
            float bv = bias[col] * ((col < 1024) ? SCQ : 1.0f);
            #pragma unroll
            for (int mi = 0; mi < 4; ++mi) {
                int row = m0 + wm + mi * 16 + quad * 4;
                #pragma unroll
                for (int r = 0; r < 4; ++r)
                    C[(size_t)(row + r) * N + col] = f2bf(acc[mi][ni][r] + bv);
            }
        }
    } else {
        float* C = (float*)Cout;
        #pragma unroll
        for (int ni = 0; ni < NI; ++ni) {
            int col = n0 + wn + ni * 16 + l16;
            #pragma unroll
            for (int mi = 0; mi < 4; ++mi) {
                int row = m0 + wm + mi * 16 + quad * 4;
                #pragma unroll
                for (int r = 0; r < 4; ++r)
                    C[(size_t)(row + r) * N + col] = acc[mi][ni][r] + yres[(size_t)(row + r) * N + col];
            }
        }
    }
}

// ---------- V transpose: qkv V-part -> vtg[b,h][d][k] (k contiguous) ----------
__global__ __launch_bounds__(256) void k_vt(const unsigned short* __restrict__ qkv,
                                            unsigned short* __restrict__ vtg) {
    __shared__ unsigned short T[64 * 72];
    const int t = threadIdx.x;
    const int k0 = blockIdx.x * 64, h = blockIdx.y, b = blockIdx.z;
    const unsigned short* vbase = qkv + (size_t)(b * 2048) * 3072 + 2048 + h * 64;
    #pragma unroll
    for (int i = 0; i < 2; ++i) {
        int B = i * 256 + t;                       // 0..511
        int row = B >> 3, c = B & 7;
        short8 v = *(const short8*)(vbase + (size_t)(k0 + row) * 3072 + c * 8);
        *(short8*)&T[row * 72 + c * 8] = v;
    }
    __syncthreads();
    unsigned short* obase = vtg + ((size_t)((b * 16 + h) * 64)) * 2048 + k0;
    #pragma unroll
    for (int i = 0; i < 2; ++i) {
        int B = i * 256 + t;
        int d = B >> 3, kc = B & 7;
        union { unsigned short u[8]; short8 v; } pk;
        #pragma unroll
        for (int jj = 0; jj < 8; ++jj) pk.u[jj] = T[(kc * 8 + jj) * 72 + d];
        *(short8*)(obase + (size_t)d * 2048 + kc * 8) = pk.v;
    }
}

// ---------- fused flash attention (q-tile 64, 4 blocks/CU, MFMA l-sum) ----------
// Tiles stored as 64-short rows; 16B chunk c of row r lives at chunk slot c^(r&7).
// Q pre-scaled by log2(e)/sqrt(64) => p = exp2(sacc), shift-free softmax.
// l computed by MFMA with an all-ones B fragment (row-sum of P), landing in the
// accumulator with rows matching each lane's store rows — no shuffles needed.
__global__ __launch_bounds__(256, 4) void k_attn(const unsigned short* __restrict__ qkv,
                                                 const unsigned short* __restrict__ vtg,
                                                 unsigned short* __restrict__ o) {
    __shared__ unsigned short LDS[20480];          // 40 KB -> 4 blocks/CU
    unsigned short* Qs = LDS;                      // [64][64] swizzled (aliased by Ps)
    unsigned short* Ps = LDS;                      // [64][64] (rows=q, cols=k)
    unsigned short* Ks0 = LDS + 4096;              // [2][64][64]
    unsigned short* Vt0 = LDS + 12288;             // [2][64][64]  (rows=d, cols=k)

    const int t = threadIdx.x;
    const int lane = t & 63, wave = t >> 6;
    const int l16 = lane & 15, quad = lane >> 4;
    const int l8 = l16 & 7;
    const int q0 = blockIdx.x * 64;
    const int h = blockIdx.y, b = blockIdx.z;

    const unsigned short* qbase = qkv + (size_t)(b * 2048) * 3072 + h * 64;
    const unsigned short* kbase = qbase + 1024;
    const unsigned short* vtbase = vtg + (size_t)((b * 16 + h) * 64) * 2048;

    // stage Q tile [64][64] swizzled
    #pragma unroll
    for (int i = 0; i < 2; ++i) {
        int B = i * 256 + t;                       // 16B-block index 0..511
        int row = B >> 3, c = (B & 7) ^ (row & 7);
        gl_lds16(qbase + (size_t)(q0 + row) * 3072 + c * 8, &Qs[B * 8]);
    }

    // per-lane staging constants for K / Vt tiles (512 blocks each)
    const int B0 = t, B1 = t + 256;
    const int r0 = B0 >> 3, c0 = (B0 & 7) ^ (r0 & 7);
    const int r1 = B1 >> 3, c1 = (B1 & 7) ^ (r1 & 7);
    const unsigned short* kp0 = kbase + (size_t)r0 * 3072 + c0 * 8;
    const unsigned short* kp1 = kbase + (size_t)r1 * 3072 + c1 * 8;
    const unsigned short* vp0 = vtbase + (size_t)r0 * 2048 + c0 * 8;
    const unsigned short* vp1 = vtbase + (size_t)r1 * 2048 + c1 * 8;

    // prefetch tile 0 into buffer 0
    gl_lds16(kp0, &Ks0[B0 * 8]);
    gl_lds16(kp1, &Ks0[B1 * 8]);
    gl_lds16(vp0, &Vt0[B0 * 8]);
    gl_lds16(vp1, &Vt0[B1 * 8]);
    kp0 += 64 * 3072; kp1 += 64 * 3072; vp0 += 64; vp1 += 64;

    __syncthreads();                               // Q + tile0 staged & visible

    // preload Q B-fragments (loop-invariant): B[n=q][k=d], n = wave*16 + l16
    short8 qf[2];
    #pragma unroll
    for (int kk = 0; kk < 2; ++kk)
        qf[kk] = *(const short8*)&Qs[(wave * 16 + l16) * 64 + ((kk * 4 + quad) ^ l8) * 8];

    __syncthreads();                               // all qf reads done before any Ps write

    f32x4 acc_o[4];
    #pragma unroll
    for (int nd = 0; nd < 4; ++nd) acc_o[nd] = zero4();
    f32x4 acc_l = zero4();
    short8 ones;
    #pragma unroll
    for (int i = 0; i < 8; ++i) ones[i] = (short)0x3F80;   // bf16 1.0

    for (int j = 0; j < 32; ++j) {
        const unsigned short* Ks = Ks0 + (j & 1) * 4096;
        const unsigned short* Vt = Vt0 + (j & 1) * 4096;

        // prefetch tile j+1 into the other buffer (overlaps this iter's compute)
        if (j < 31) {
            unsigned short* Kn = Ks0 + ((j + 1) & 1) * 4096;
            unsigned short* Vn = Vt0 + ((j + 1) & 1) * 4096;
            gl_lds16(kp0, &Kn[B0 * 8]);
            gl_lds16(kp1, &Kn[B1 * 8]);
            gl_lds16(vp0, &Vn[B0 * 8]);
            gl_lds16(vp1, &Vn[B1 * 8]);
            kp0 += 64 * 3072; kp1 += 64 * 3072; vp0 += 64; vp1 += 64;
        }

        // S^T = K @ Q^T : per wave [64 k x 16 q]
        f32x4 sacc[4];
        #pragma unroll
        for (int mi = 0; mi < 4; ++mi) sacc[mi] = zero4();
        #pragma unroll
        for (int kk = 0; kk < 2; ++kk)
            #pragma unroll
            for (int mi = 0; mi < 4; ++mi) {
                short8 kf = *(const short8*)&Ks[(mi * 16 + l16) * 64 + ((kk * 4 + quad) ^ l8) * 8];
                sacc[mi] = __builtin_amdgcn_mfma_f32_16x16x32_bf16(kf, qf[kk], sacc[mi], 0, 0, 0);
            }

        // p = exp2(sacc) (single v_exp_f32), pack to bf16, write Ps[q][k]
        {
            int qrow = wave * 16 + l16;
            #pragma unroll
            for (int mi = 0; mi < 4; ++mi) {
                float p0 = __builtin_amdgcn_exp2f(sacc[mi][0]);
                float p1 = __builtin_amdgcn_exp2f(sacc[mi][1]);
                float p2 = __builtin_amdgcn_exp2f(sacc[mi][2]);
                float p3 = __builtin_amdgcn_exp2f(sacc[mi][3]);
                uint2 w; w.x = pack2bf(p0, p1); w.y = pack2bf(p2, p3);
                *(uint2*)&Ps[qrow * 64 + ((2 * mi + (quad >> 1)) ^ l8) * 8 + (quad & 1) * 4] = w;
            }
        }

        // PV + l: O[q][d] += P @ V, l[q] += P @ 1 (Ps rows wave-private; DS in-order per wave)
        #pragma unroll
        for (int kk = 0; kk < 2; ++kk) {
            short8 pf = *(const short8*)&Ps[(wave * 16 + l16) * 64 + ((kk * 4 + quad) ^ l8) * 8];
            acc_l = __builtin_amdgcn_mfma_f32_16x16x32_bf16(pf, ones, acc_l, 0, 0, 0);
            #pragma unroll
            for (int nd = 0; nd < 4; ++nd) {
                short8 vf = *(const short8*)&Vt[(nd * 16 + l16) * 64 + ((kk * 4 + quad) ^ l8) * 8];
                acc_o[nd] = __builtin_amdgcn_mfma_f32_16x16x32_bf16(pf, vf, acc_o[nd], 0, 0, 0);
            }
        }

        __syncthreads();   // cur-tile reads done everywhere; drains prefetch (issued a full iter ago)
    }

    // epilogue: lane holds rows q = q0 + wave*16 + quad*4 + rr; acc_l[rr] is that row's l
    #pragma unroll
    for (int rr = 0; rr < 4; ++rr) {
        float inv = __builtin_amdgcn_rcpf(acc_l[rr]);
        int qg = q0 + wave * 16 + quad * 4 + rr;
        size_t base = ((size_t)(b * 2048 + qg)) * 1024 + h * 64;
        #pragma unroll
        for (int nd = 0; nd < 4; ++nd)
            o[base + nd * 16 + l16] = f2bf(acc_o[nd][rr] * inv);
    }
}

// ---------- LayerNorm (row=token, 1024 cols), fp32 in/out ----------
__global__ __launch_bounds__(256) void k_ln(const float* __restrict__ res,
                                            const float* __restrict__ g,
                                            const float* __restrict__ be,
                                            float* __restrict__ out) {
    __shared__ float red[8];
    const int row = blockIdx.x, t = threadIdx.x;
    const float* x = res + (size_t)row * 1024;
    float4 v = *(const float4*)(x + t * 4);
    float s = v.x + v.y + v.z + v.w;
    float sq = v.x * v.x + v.y * v.y + v.z * v.z + v.w * v.w;
    #pragma unroll
    for (int off = 32; off; off >>= 1) { s += __shfl_down(s, off); sq += __shfl_down(sq, off); }
    if ((t & 63) == 0) { red[t >> 6] = s; red[4 + (t >> 6)] = sq; }
    __syncthreads();
    float ts = red[0] + red[1] + red[2] + red[3];
    float tq = red[4] + red[5] + red[6] + red[7];
    float mu = ts * (1.f / 1024.f);
    float var = tq * (1.f / 1024.f) - mu * mu;
    float rstd = rsqrtf(var + 1e-6f);
    float4 gg = *(const float4*)(g + t * 4);
    float4 bb = *(const float4*)(be + t * 4);
    float4 ov;
    ov.x = (v.x - mu) * rstd * gg.x + bb.x;
    ov.y = (v.y - mu) * rstd * gg.y + bb.y;
    ov.z = (v.z - mu) * rstd * gg.z + bb.z;
    ov.w = (v.w - mu) * rstd * gg.w + bb.w;
    *(float4*)(out + (size_t)row * 1024 + t * 4) = ov;
}

// ---------- launch ----------
extern "C" void kernel_launch(void* const* d_in, const int* in_sizes, int n_in,
                              void* d_out, int out_size, void* d_ws, size_t ws_size,
                              hipStream_t stream) {
    (void)in_sizes; (void)n_in; (void)out_size; (void)ws_size;
    const float* y    = (const float*)d_in[0];
    const float* Wqkv = (const float*)d_in[1];
    const float* bqkv = (const float*)d_in[2];
    const float* Wmsa = (const float*)d_in[3];
    const float* Bq = (const float*)d_in[4];
    const float* Aq = (const float*)d_in[5];
    const float* Bk = (const float*)d_in[6];
    const float* Ak = (const float*)d_in[7];
    const float* Bv = (const float*)d_in[8];
    const float* Av = (const float*)d_in[9];
    const float* Bo = (const float*)d_in[10];
    const float* Ao = (const float*)d_in[11];
    const float* gamma = (const float*)d_in[12];
    const float* beta  = (const float*)d_in[13];

    char* ws = (char*)d_ws;
    unsigned short* yb   = (unsigned short*)(ws);               // 8 MB bf16(y); reused as obuf
    unsigned short* weq  = (unsigned short*)(ws + (8u  << 20)); // 6 MB [3072][1024], wem contiguous after
    unsigned short* qkv  = (unsigned short*)(ws + (16u << 20)); // 24 MB [4096][3072]; reused as res (fp32 16 MB)
    unsigned short* vtg  = (unsigned short*)(ws + (40u << 20)); // 8 MB [32][64][2048] V^T
    unsigned short* wem  = weq + 3145728;                       // 2 MB [1024][1024]
    unsigned short* obuf = yb;
    float* res = (float*)qkv;

    k_prep<<<17408, 256, 0, stream>>>(y, Wqkv, Wmsa, Bq, Aq, Bk, Ak, Bv, Av, Bo, Ao, weq, yb);
    k_gemm<128, 0, 3><<<dim3(24, 32), 256, 0, stream>>>(yb, weq, bqkv, nullptr, (void*)qkv, 4096, 3072, 1024);
    k_vt  <<<dim3(32, 16, 2), 256, 0, stream>>>(qkv, vtg);
    k_attn<<<dim3(32, 16, 2), 256, 0, stream>>>(qkv, vtg, obuf);
    k_gemm<64, 1, 4><<<dim3(8, 64), 256, 0, stream>>>(obuf, wem, nullptr, y, (void*)res, 4096, 1024, 1024);
    k_ln  <<<4096, 256, 0, stream>>>(res, gamma, beta, (float*)d_out);
}

// Round 8
// 214.339 us; speedup vs baseline: 1.4011x; 1.0299x over previous
//
#include <hip/hip_runtime.h>
#include <hip/hip_bf16.h>
#include <stdint.h>

// ---------- types ----------
typedef __attribute__((ext_vector_type(8))) short short8;   // 8 x bf16 (raw)
typedef __attribute__((ext_vector_type(4))) float f32x4;

typedef const __attribute__((address_space(1))) void gv_t;
typedef __attribute__((address_space(3))) void lv_t;

#define SCQ 0.18033688011112042f   // log2(e)/sqrt(64), folded into Q projection

__device__ __forceinline__ void gl_lds16(const void* g, void* l) {
    // async global->LDS, 16B per lane; LDS dest must be waveBase + lane*16
    __builtin_amdgcn_global_load_lds((gv_t*)g, (lv_t*)l, 16, 0, 0);
}

__device__ __forceinline__ unsigned short f2bf(float f) {
    union { float f; unsigned int u; } v; v.f = f;
    unsigned int r = v.u + 0x7fffu + ((v.u >> 16) & 1u);   // RNE
    return (unsigned short)(r >> 16);
}

__device__ __forceinline__ unsigned int pack2bf(float a, float b) {
    union { __hip_bfloat162 h2; unsigned int u; } cv;
    cv.h2 = __float22bfloat162_rn(make_float2(a, b));   // v_cvt_pk_bf16_f32 on gfx950
    return cv.u;                                        // low = a, high = b
}

__device__ __forceinline__ f32x4 zero4() { f32x4 z = {0.f, 0.f, 0.f, 0.f}; return z; }

// ---------- fused prep: LoRA weight fold (Wqkv & Wmsa) + y->bf16 cvt ----------
__global__ void k_prep(const float* __restrict__ y,
                       const float* __restrict__ Wqkv, const float* __restrict__ Wmsa,
                       const float* __restrict__ Bq, const float* __restrict__ Aq,
                       const float* __restrict__ Bk, const float* __restrict__ Ak,
                       const float* __restrict__ Bv, const float* __restrict__ Av,
                       const float* __restrict__ Bo, const float* __restrict__ Ao,
                       unsigned short* __restrict__ wout, unsigned short* __restrict__ yb) {
    const int bid = blockIdx.x;
    if (bid < 16384) {
        int idx = bid * 256 + threadIdx.x;     // n*1024 + k, n in [0,4096)
        int n = idx >> 10, k = idx & 1023;
        int sel = n >> 10, n0 = n & 1023;
        const float* Bp = (sel == 0) ? Bq : (sel == 1) ? Bk : (sel == 2) ? Bv : Bo;
        const float* Ap = (sel == 0) ? Aq : (sel == 1) ? Ak : (sel == 2) ? Av : Ao;
        float acc = (sel < 3) ? Wqkv[idx] : Wmsa[idx - 3145728];
        #pragma unroll
        for (int r = 0; r < 8; ++r) acc += Bp[k * 8 + r] * Ap[r * 1024 + n0];
        wout[idx] = f2bf(acc * ((sel == 0) ? SCQ : 1.0f));
    } else {
        int i = ((bid - 16384) * 256 + threadIdx.x) * 4;
        float4 v = *(const float4*)(y + i);
        union { unsigned short u[4]; uint2 w; } o;
        o.u[0] = f2bf(v.x); o.u[1] = f2bf(v.y); o.u[2] = f2bf(v.z); o.u[3] = f2bf(v.w);
        *(uint2*)(yb + i) = o.w;
    }
}

// ---------- GEMM: C[M,N] = A[M,K](bf16) @ B[N,K]^T(bf16), dbuf cross-barrier prefetch ----------
// EPI=0: bf16(acc+bias[col]); cols<1024 get SCQ on bias; cols>=2048 (V) are written
//        TRANSPOSED into vtg[b,h][d][tok] (4 tokens packed per store) — k_vt folded in.
// EPI=1: fp32(acc + yres).
template <int TM, int EPI, int MINW>
__global__ __launch_bounds__(256, MINW) void k_gemm(const unsigned short* __restrict__ Ag,
                                                    const unsigned short* __restrict__ Bg,
                                                    const float* __restrict__ bias,
                                                    const float* __restrict__ yres,
                                                    unsigned short* __restrict__ vtg,
                                                    void* __restrict__ Cout,
                                                    int M, int N, int K) {
    constexpr int WAVES_N = 256 / TM;
    constexpr int WN = TM / 2;
    constexpr int NI = WN / 16;
    constexpr int ACALLS = TM / 64;
    __shared__ unsigned short As[2][TM * 32];
    __shared__ unsigned short Bs[2][128 * 32];
    const int flat = threadIdx.x;
    const int m0 = blockIdx.y * TM, n0 = blockIdx.x * 128;
    const int lane = flat & 63, wave = flat >> 6;
    const int l16 = lane & 15, quad = lane >> 4;
    const int wm = (wave / WAVES_N) * 64, wn = (wave % WAVES_N) * WN;

    f32x4 acc[4][NI];
    #pragma unroll
    for (int mi = 0; mi < 4; ++mi)
        #pragma unroll
        for (int ni = 0; ni < NI; ++ni) acc[mi][ni] = zero4();

    const unsigned short* ap = Ag + (size_t)(m0 + (flat >> 2)) * K + (flat & 3) * 8;
    const unsigned short* bp = Bg + (size_t)(n0 + (flat >> 2)) * K + (flat & 3) * 8;
    const size_t rstep = (size_t)64 * K;

    #pragma unroll
    for (int c = 0; c < ACALLS; ++c) gl_lds16(ap + c * rstep, &As[0][c * 2048 + flat * 8]);
    gl_lds16(bp,         &Bs[0][flat * 8]);
    gl_lds16(bp + rstep, &Bs[0][2048 + flat * 8]);
    ap += 32; bp += 32;
    __syncthreads();

    for (int k0 = 0; k0 < K; k0 += 32) {
        const int cur = (k0 >> 5) & 1;
        if (k0 + 32 < K) {
            const int nxt = cur ^ 1;
            #pragma unroll
            for (int c = 0; c < ACALLS; ++c) gl_lds16(ap + c * rstep, &As[nxt][c * 2048 + flat * 8]);
            gl_lds16(bp,         &Bs[nxt][flat * 8]);
            gl_lds16(bp + rstep, &Bs[nxt][2048 + flat * 8]);
            ap += 32; bp += 32;
        }

        short8 af[4], bfr[NI];
        #pragma unroll
        for (int i = 0; i < 4; ++i) af[i] = *(const short8*)&As[cur][(wm + i * 16 + l16) * 32 + quad * 8];
        #pragma unroll
        for (int i = 0; i < NI; ++i) bfr[i] = *(const short8*)&Bs[cur][(wn + i * 16 + l16) * 32 + quad * 8];
        #pragma unroll
        for (int mi = 0; mi < 4; ++mi)
            #pragma unroll
            for (int ni = 0; ni < NI; ++ni)
                acc[mi][ni] = __builtin_amdgcn_mfma_f32_16x16x32_bf16(af[mi], bfr[ni], acc[mi][ni], 0, 0, 0);

        __syncthreads();
    }

    // epilogue: C/D layout col=lane&15, row=quad*4+reg
    if (EPI == 0) {
        unsigned short* C = (unsigned short*)Cout;
        if (n0 < 2048) {      // Q/K columns: normal row-major bf16 store
            #pragma unroll
            for (int ni = 0; ni < NI; ++ni) {
                int col = n0 + wn + ni * 16 + l16;
                float bv = bias[col] * ((col < 1024) ? SCQ : 1.0f);
                #pragma unroll
                for (int mi = 0; mi < 4; ++mi) {
                    int row = m0 + wm + mi * 16 + quad * 4;
                    #pragma unroll
                    for (int r = 0; r < 4; ++r)
                        C[(size_t)(row + r) * N + col] = f2bf(acc[mi][ni][r] + bv);
                }
            }
        } else {              // V columns: write transposed into vtg[(b*16+h)*64+d][tok]
            #pragma unroll
            for (int ni = 0; ni < NI; ++ni) {
                int col = n0 + wn + ni * 16 + l16;
                float bv = bias[col];
                int hh = (col - 2048) >> 6, dd = col & 63;
                unsigned short* vrow0 = vtg + (size_t)(hh * 64 + dd) * 2048;
                #pragma unroll
                for (int mi = 0; mi < 4; ++mi) {
                    int row = m0 + wm + mi * 16 + quad * 4;
                    int bb = row >> 11, ss = row & 2047;
                    uint2 w;
                    w.x = pack2bf(acc[mi][ni][0] + bv, acc[mi][ni][1] + bv);
                    w.y = pack2bf(acc[mi][ni][2] + bv, acc[mi][ni][3] + bv);
                    *(uint2*)(vrow0 + (size_t)bb * 2097152 + ss) = w;   // 16*64*2048 = 2,097,152
                }
            }
        }
    } else {
        float* C = (float*)Cout;
        #pragma unroll
        for (int ni = 0; ni < NI; ++ni) {
            int col = n0 + wn + ni * 16 + l16;
            #pragma unroll
            for (int mi = 0; mi < 4; ++mi) {
                int row = m0 + wm + mi * 16 + quad * 4;
                #pragma unroll
                for (int r = 0; r < 4; ++r)
                    C[(size_t)(row + r) * N + col] = acc[mi][ni][r] + yres[(size_t)(row + r) * N + col];
            }
        }
    }
}

// ---------- fused flash attention (q-tile 128, 32 q/wave: amortizes K/V LDS reads) ----------
// Tiles stored as 64-short rows; 16B chunk c of row r lives at chunk slot c^(r&7).
// Q pre-scaled by log2(e)/sqrt(64) => p = exp2(sacc), shift-free softmax.
// l via MFMA ones-trick: row-sum of P lands in accumulator rows matching store rows.
__global__ __launch_bounds__(256, 3) void k_attn(const unsigned short* __restrict__ qkv,
                                                 const unsigned short* __restrict__ vtg,
                                                 unsigned short* __restrict__ o) {
    __shared__ unsigned short LDS[24576];          // 48 KB
    unsigned short* Qs = LDS;                      // [128][64] swizzled (aliased by Ps)
    unsigned short* Ps = LDS;                      // [128][64] (rows=q, cols=k)
    unsigned short* Ks0 = LDS + 8192;              // [2][64][64]
    unsigned short* Vt0 = LDS + 16384;             // [2][64][64]  (rows=d, cols=k)

    const int t = threadIdx.x;
    const int lane = t & 63, wave = t >> 6;
    const int l16 = lane & 15, quad = lane >> 4;
    const int l8 = l16 & 7;
    const int q0 = blockIdx.x * 128;
    const int h = blockIdx.y, b = blockIdx.z;

    const unsigned short* qbase = qkv + (size_t)(b * 2048) * 3072 + h * 64;
    const unsigned short* kbase = qbase + 1024;
    const unsigned short* vtbase = vtg + (size_t)((b * 16 + h) * 64) * 2048;

    // stage Q tile [128][64] swizzled
    #pragma unroll
    for (int i = 0; i < 4; ++i) {
        int B = i * 256 + t;                       // 16B-block index 0..1023
        int row = B >> 3, c = (B & 7) ^ (row & 7);
        gl_lds16(qbase + (size_t)(q0 + row) * 3072 + c * 8, &Qs[B * 8]);
    }

    // per-lane staging constants for K / Vt tiles (512 blocks each)
    const int B0 = t, B1 = t + 256;
    const int r0 = B0 >> 3, c0 = (B0 & 7) ^ (r0 & 7);
    const int r1 = B1 >> 3, c1 = (B1 & 7) ^ (r1 & 7);
    const unsigned short* kp0 = kbase + (size_t)r0 * 3072 + c0 * 8;
    const unsigned short* kp1 = kbase + (size_t)r1 * 3072 + c1 * 8;
    const unsigned short* vp0 = vtbase + (size_t)r0 * 2048 + c0 * 8;
    const unsigned short* vp1 = vtbase + (size_t)r1 * 2048 + c1 * 8;

    // prefetch tile 0 into buffer 0
    gl_lds16(kp0, &Ks0[B0 * 8]);
    gl_lds16(kp1, &Ks0[B1 * 8]);
    gl_lds16(vp0, &Vt0[B0 * 8]);
    gl_lds16(vp1, &Vt0[B1 * 8]);
    kp0 += 64 * 3072; kp1 += 64 * 3072; vp0 += 64; vp1 += 64;

    __syncthreads();                               // Q + tile0 staged & visible

    // preload Q B-fragments (loop-invariant): B[n=q][k=d], n = wave*32 + ni*16 + l16
    short8 qf[2][2];
    #pragma unroll
    for (int ni = 0; ni < 2; ++ni)
        #pragma unroll
        for (int kk = 0; kk < 2; ++kk)
            qf[ni][kk] = *(const short8*)&Qs[(wave * 32 + ni * 16 + l16) * 64 + ((kk * 4 + quad) ^ l8) * 8];

    __syncthreads();                               // all qf reads done before any Ps write

    f32x4 acc_o[2][4];
    #pragma unroll
    for (int mo = 0; mo < 2; ++mo)
        #pragma unroll
        for (int nd = 0; nd < 4; ++nd) acc_o[mo][nd] = zero4();
    f32x4 acc_l[2] = {zero4(), zero4()};
    short8 ones;
    #pragma unroll
    for (int i = 0; i < 8; ++i) ones[i] = (short)0x3F80;   // bf16 1.0

    for (int j = 0; j < 32; ++j) {
        const unsigned short* Ks = Ks0 + (j & 1) * 4096;
        const unsigned short* Vt = Vt0 + (j & 1) * 4096;

        // prefetch tile j+1 into the other buffer (overlaps this iter's compute)
        if (j < 31) {
            unsigned short* Kn = Ks0 + ((j + 1) & 1) * 4096;
            unsigned short* Vn = Vt0 + ((j + 1) & 1) * 4096;
            gl_lds16(kp0, &Kn[B0 * 8]);
            gl_lds16(kp1, &Kn[B1 * 8]);
            gl_lds16(vp0, &Vn[B0 * 8]);
            gl_lds16(vp1, &Vn[B1 * 8]);
            kp0 += 64 * 3072; kp1 += 64 * 3072; vp0 += 64; vp1 += 64;
        }

        // S^T = K @ Q^T : per wave [64 k x 32 q]
        f32x4 sacc[4][2];
        #pragma unroll
        for (int mi = 0; mi < 4; ++mi)
            #pragma unroll
            for (int ni = 0; ni < 2; ++ni) sacc[mi][ni] = zero4();
        #pragma unroll
        for (int kk = 0; kk < 2; ++kk)
            #pragma unroll
            for (int mi = 0; mi < 4; ++mi) {
                short8 kf = *(const short8*)&Ks[(mi * 16 + l16) * 64 + ((kk * 4 + quad) ^ l8) * 8];
                #pragma unroll
                for (int ni = 0; ni < 2; ++ni)
                    sacc[mi][ni] = __builtin_amdgcn_mfma_f32_16x16x32_bf16(kf, qf[ni][kk], sacc[mi][ni], 0, 0, 0);
            }

        // p = exp2(sacc) (single v_exp_f32 each), pack to bf16, write Ps[q][k]
        #pragma unroll
        for (int ni = 0; ni < 2; ++ni) {
            int qrow = wave * 32 + ni * 16 + l16;
            #pragma unroll
            for (int mi = 0; mi < 4; ++mi) {
                float p0 = __builtin_amdgcn_exp2f(sacc[mi][ni][0]);
                float p1 = __builtin_amdgcn_exp2f(sacc[mi][ni][1]);
                float p2 = __builtin_amdgcn_exp2f(sacc[mi][ni][2]);
                float p3 = __builtin_amdgcn_exp2f(sacc[mi][ni][3]);
                uint2 w; w.x = pack2bf(p0, p1); w.y = pack2bf(p2, p3);
                *(uint2*)&Ps[qrow * 64 + ((2 * mi + (quad >> 1)) ^ l8) * 8 + (quad & 1) * 4] = w;
            }
        }

        // PV + l: O[q][d] += P @ V, l[q] += P @ 1 (Ps rows wave-private; DS in-order per wave)
        #pragma unroll
        for (int kk = 0; kk < 2; ++kk) {
            short8 pf[2];
            #pragma unroll
            for (int mo = 0; mo < 2; ++mo) {
                pf[mo] = *(const short8*)&Ps[(wave * 32 + mo * 16 + l16) * 64 + ((kk * 4 + quad) ^ l8) * 8];
                acc_l[mo] = __builtin_amdgcn_mfma_f32_16x16x32_bf16(pf[mo], ones, acc_l[mo], 0, 0, 0);
            }
            #pragma unroll
            for (int nd = 0; nd < 4; ++nd) {
                short8 vf = *(const short8*)&Vt[(nd * 16 + l16) * 64 + ((kk * 4 + quad) ^ l8) * 8];
                #pragma unroll
                for (int mo = 0; mo < 2; ++mo)
                    acc_o[mo][nd] = __builtin_amdgcn_mfma_f32_16x16x32_bf16(pf[mo], vf, acc_o[mo][nd], 0, 0, 0);
            }
        }

        __syncthreads();   // cur-tile reads done everywhere; drains prefetch (issued a full iter ago)
    }

    // epilogue: lane holds rows q = q0 + wave*32 + mo*16 + quad*4 + rr; acc_l[mo][rr] is l
    #pragma unroll
    for (int mo = 0; mo < 2; ++mo)
        #pragma unroll
        for (int rr = 0; rr < 4; ++rr) {
            float inv = 1.0f / acc_l[mo][rr];
            int qg = q0 + wave * 32 + mo * 16 + quad * 4 + rr;
            size_t base = ((size_t)(b * 2048 + qg)) * 1024 + h * 64;
            #pragma unroll
            for (int nd = 0; nd < 4; ++nd)
                o[base + nd * 16 + l16] = f2bf(acc_o[mo][nd][rr] * inv);
        }
}

// ---------- LayerNorm (row=token, 1024 cols), fp32 in/out ----------
__global__ __launch_bounds__(256) void k_ln(const float* __restrict__ res,
                                            const float* __restrict__ g,
                                            const float* __restrict__ be,
                                            float* __restrict__ out) {
    __shared__ float red[8];
    const int row = blockIdx.x, t = threadIdx.x;
    const float* x = res + (size_t)row * 1024;
    float4 v = *(const float4*)(x + t * 4);
    float s = v.x + v.y + v.z + v.w;
    float sq = v.x * v.x + v.y * v.y + v.z * v.z + v.w * v.w;
    #pragma unroll
    for (int off = 32; off; off >>= 1) { s += __shfl_down(s, off); sq += __shfl_down(sq, off); }
    if ((t & 63) == 0) { red[t >> 6] = s; red[4 + (t >> 6)] = sq; }
    __syncthreads();
    float ts = red[0] + red[1] + red[2] + red[3];
    float tq = red[4] + red[5] + red[6] + red[7];
    float mu = ts * (1.f / 1024.f);
    float var = tq * (1.f / 1024.f) - mu * mu;
    float rstd = rsqrtf(var + 1e-6f);
    float4 gg = *(const float4*)(g + t * 4);
    float4 bb = *(const float4*)(be + t * 4);
    float4 ov;
    ov.x = (v.x - mu) * rstd * gg.x + bb.x;
    ov.y = (v.y - mu) * rstd * gg.y + bb.y;
    ov.z = (v.z - mu) * rstd * gg.z + bb.z;
    ov.w = (v.w - mu) * rstd * gg.w + bb.w;
    *(float4*)(out + (size_t)row * 1024 + t * 4) = ov;
}

// ---------- launch ----------
extern "C" void kernel_launch(void* const* d_in, const int* in_sizes, int n_in,
                              void* d_out, int out_size, void* d_ws, size_t ws_size,
                              hipStream_t stream) {
    (void)in_sizes; (void)n_in; (void)out_size; (void)ws_size;
    const float* y    = (const float*)d_in[0];
    const float* Wqkv = (const float*)d_in[1];
    const float* bqkv = (const float*)d_in[2];
    const float* Wmsa = (const float*)d_in[3];
    const float* Bq = (const float*)d_in[4];
    const float* Aq = (const float*)d_in[5];
    const float* Bk = (const float*)d_in[6];
    const float* Ak = (const float*)d_in[7];
    const float* Bv = (const float*)d_in[8];
    const float* Av = (const float*)d_in[9];
    const float* Bo = (const float*)d_in[10];
    const float* Ao = (const float*)d_in[11];
    const float* gamma = (const float*)d_in[12];
    const float* beta  = (const float*)d_in[13];

    char* ws = (char*)d_ws;
    unsigned short* yb   = (unsigned short*)(ws);               // 8 MB bf16(y); reused as obuf
    unsigned short* weq  = (unsigned short*)(ws + (8u  << 20)); // 6 MB [3072][1024], wem contiguous after
    unsigned short* qkv  = (unsigned short*)(ws + (16u << 20)); // 24 MB [4096][3072] (V part unused); reused as res
    unsigned short* vtg  = (unsigned short*)(ws + (40u << 20)); // 8 MB [32][64][2048] V^T
    unsigned short* wem  = weq + 3145728;                       // 2 MB [1024][1024]
    unsigned short* obuf = yb;
    float* res = (float*)qkv;

    k_prep<<<17408, 256, 0, stream>>>(y, Wqkv, Wmsa, Bq, Aq, Bk, Ak, Bv, Av, Bo, Ao, weq, yb);
    k_gemm<128, 0, 3><<<dim3(24, 32), 256, 0, stream>>>(yb, weq, bqkv, nullptr, vtg, (void*)qkv, 4096, 3072, 1024);
    k_attn<<<dim3(16, 16, 2), 256, 0, stream>>>(qkv, vtg, obuf);
    k_gemm<64, 1, 4><<<dim3(8, 64), 256, 0, stream>>>(obuf, wem, nullptr, y, nullptr, (void*)res, 4096, 1024, 1024);
    k_ln  <<<4096, 256, 0, stream>>>(res, gamma, beta, (float*)d_out);
}